// Round 17
// baseline (482.965 us; speedup 1.0000x reference)
//
#include <hip/hip_runtime.h>
#include <hip/hip_bf16.h>
#include <hip/hip_fp16.h>

#define B_ 128
#define F_ 64
#define R_ 32

typedef __attribute__((ext_vector_type(8))) __bf16 bf16x8;
typedef __attribute__((ext_vector_type(4))) float f32x4;

#define LN2F 0.6931471805599453f
#define L2EF 1.4426950408889634f

// ssp(x) = max(x,0) + ln2*log2(1+2^(-log2e*|x|)) - ln2   (overflow-safe all x)
__device__ __forceinline__ float sspf(float x) {
    float t = fabsf(x) * (-L2EF);
    float e; asm("v_exp_f32 %0, %1" : "=v"(e) : "v"(t));
    float l; asm("v_log_f32 %0, %1" : "=v"(l) : "v"(1.0f + e));
    return fmaxf(x, 0.0f) + fmaf(LN2F, l, -LN2F);
}
__device__ __forceinline__ float bfbits2f(unsigned int us) { return __uint_as_float(us << 16); }
__device__ __forceinline__ unsigned int f2bf(float f) {
    unsigned int u = __float_as_uint(f);
    return (u + 0x7fffu + ((u >> 16) & 1u)) >> 16;   // RNE
}
__device__ __forceinline__ float h16f(unsigned short s) { return __half2float(__ushort_as_half(s)); }
// packed HW conversions (v_cvt_pk_*): bit-pattern via memcpy (free)
__device__ __forceinline__ unsigned int pkbf(float a, float b) {
    __hip_bfloat162 h = __float22bfloat162_rn(make_float2(a, b));
    unsigned int r; __builtin_memcpy(&r, &h, 4); return r;
}
__device__ __forceinline__ unsigned int pkh(float a, float b) {
    __half2 h = __float22half2_rn(make_float2(a, b));
    unsigned int r; __builtin_memcpy(&r, &h, 4); return r;
}

// ---- front: prepack (blocks 0-14) + detect (15) + h (next hgrid) + hist (rest) ----
__global__ __launch_bounds__(256) void front_kernel(
    const float* __restrict__ w1, const float* __restrict__ w2,
    const float* __restrict__ wo1, const float* __restrict__ wo2,
    unsigned short* __restrict__ w1p, unsigned short* __restrict__ w2p,
    unsigned short* __restrict__ wo1p, unsigned short* __restrict__ wo2p,
    const void* __restrict__ pl, int* __restrict__ flag, int P,
    const float* __restrict__ x, const float* __restrict__ w_in,
    const float* __restrict__ b_in, unsigned short* __restrict__ h, int NA,
    int* __restrict__ hist, int hgrid)
{
    int b = blockIdx.x;
    if (b < 15) {
        int t = b * 256 + threadIdx.x;
        if (t < 256) {
            int ct = t >> 6, l = t & 63, g = l >> 4, m = l & 15;
            #pragma unroll
            for (int i = 0; i < 8; ++i)
                w1p[t * 8 + i] = (unsigned short)f2bf(w1[(g * 8 + i) * F_ + ct * 16 + m]);
        } else if (t < 768) {
            int q = t - 256;
            int kh = q >> 8, ct = (q >> 6) & 3, l = q & 63, g = l >> 4, m = l & 15;
            #pragma unroll
            for (int i = 0; i < 8; ++i)
                w2p[q * 8 + i] = (unsigned short)f2bf(w2[(kh * 32 + g * 8 + i) * F_ + ct * 16 + m]);
        } else if (t < 2816) {
            int q = t - 768;
            int l = q & 63, ct = (q >> 6) & 3, kh = (q >> 8) & 3, ch = q >> 10;
            int g = l >> 4, m = l & 15;
            #pragma unroll
            for (int i = 0; i < 8; ++i)
                wo2p[q * 8 + i] = (unsigned short)f2bf(wo2[(kh * 32 + g * 8 + i) * B_ + ch * 64 + ct * 16 + m]);
        } else if (t < 3840) {
            int q = t - 2816;
            int l = q & 63, ct = (q >> 6) & 3, kh = (q >> 8) & 1, ch = q >> 9;
            int g = l >> 4, m = l & 15;
            #pragma unroll
            for (int i = 0; i < 8; ++i)
                wo1p[q * 8 + i] = (unsigned short)f2bf(wo1[(kh * 32 + g * 8 + i) * B_ + ch * 64 + ct * 16 + m]);
        }
        return;
    }
    if (b == 15) {
        if (threadIdx.x < 64) {
            int n = (P < 64) ? P : 64;
            const long long* p64 = (const long long*)pl;
            bool bad = false;
            if ((int)threadIdx.x < n) {
                long long v = p64[threadIdx.x];
                bad = (v < 0) || (v >= 100000000LL);
            }
            unsigned long long bl = __ballot(bad);
            if (threadIdx.x == 0) *flag = (bl == 0ULL) ? 1 : 0;
        }
        return;
    }
    if (b < 16 + hgrid) {
        // h = x @ w_in + b_in, bf16
        int n = (b - 16) * 256 + threadIdx.x;
        if (n >= NA) return;
        float acc[F_];
        #pragma unroll
        for (int f = 0; f < F_; ++f) acc[f] = b_in[f];
        const float4* xrow = (const float4*)(x + (size_t)n * B_);
        #pragma unroll 2
        for (int rb = 0; rb < B_ / 4; ++rb) {
            float4 xv = xrow[rb];
            const float* w0 = w_in + (size_t)(4 * rb) * F_;
            #pragma unroll
            for (int f = 0; f < F_; ++f) acc[f] = fmaf(xv.x, w0[f], acc[f]);
            #pragma unroll
            for (int f = 0; f < F_; ++f) acc[f] = fmaf(xv.y, w0[F_ + f], acc[f]);
            #pragma unroll
            for (int f = 0; f < F_; ++f) acc[f] = fmaf(xv.z, w0[2 * F_ + f], acc[f]);
            #pragma unroll
            for (int f = 0; f < F_; ++f) acc[f] = fmaf(xv.w, w0[3 * F_ + f], acc[f]);
        }
        uint4* hrow = (uint4*)(h + (size_t)n * F_);
        #pragma unroll
        for (int q = 0; q < F_ / 8; ++q) {
            uint4 ob;
            ob.x = pkbf(acc[8 * q + 0], acc[8 * q + 1]);
            ob.y = pkbf(acc[8 * q + 2], acc[8 * q + 3]);
            ob.z = pkbf(acc[8 * q + 4], acc[8 * q + 5]);
            ob.w = pkbf(acc[8 * q + 6], acc[8 * q + 7]);
            hrow[q] = ob;
        }
        return;
    }
    // hist blocks: block-local dtype detect
    __shared__ int sflag;
    if (threadIdx.x < 64) {
        int n = (P < 64) ? P : 64;
        const long long* p64 = (const long long*)pl;
        bool bad = false;
        if ((int)threadIdx.x < n) {
            long long v = p64[threadIdx.x];
            bad = (v < 0) || (v >= 100000000LL);
        }
        unsigned long long bl = __ballot(bad);
        if (threadIdx.x == 0) sflag = (bl == 0ULL) ? 1 : 0;
    }
    __syncthreads();
    int p = (b - 16 - hgrid) * 256 + threadIdx.x;
    if (p >= P) return;
    int i = sflag ? (int)((const long long*)pl)[p] : ((const int*)pl)[p];
    atomicAdd(&hist[i], 1);
}

// ---- hierarchical scan, level 1 ----
__global__ __launch_bounds__(256) void scan1_kernel(
    const int* __restrict__ hist, int* __restrict__ off,
    int* __restrict__ bsum, int NA)
{
    __shared__ int s[256];
    int t = threadIdx.x;
    int idx = blockIdx.x * 2048 + t * 8;
    int v[8];
    int run = 0;
    #pragma unroll
    for (int k = 0; k < 8; ++k) {
        int i = idx + k;
        int c = (i < NA) ? hist[i] : 0;
        v[k] = run; run += c;
    }
    s[t] = run;
    __syncthreads();
    for (int o = 1; o < 256; o <<= 1) {
        int x = (t >= o) ? s[t - o] : 0;
        __syncthreads();
        s[t] += x;
        __syncthreads();
    }
    int base = (t == 0) ? 0 : s[t - 1];
    #pragma unroll
    for (int k = 0; k < 8; ++k) {
        int i = idx + k;
        if (i < NA) off[i] = v[k] + base;
    }
    if (t == 255) bsum[blockIdx.x] = s[255];
}

__global__ __launch_bounds__(256) void scan2_kernel(int* __restrict__ bsum, int nb) {
    __shared__ int s[256];
    int t = threadIdx.x;
    int v = (t < nb) ? bsum[t] : 0;
    s[t] = v;
    __syncthreads();
    for (int o = 1; o < 256; o <<= 1) {
        int x = (t >= o) ? s[t - o] : 0;
        __syncthreads();
        s[t] += x;
        __syncthreads();
    }
    if (t < nb) bsum[t] = s[t] - v;
}

__global__ __launch_bounds__(256) void scan3_kernel(
    int* __restrict__ off, int* __restrict__ cursor,
    const int* __restrict__ bsum, int NA, int P)
{
    int i = blockIdx.x * 256 + threadIdx.x;
    if (i > NA) return;
    if (i == NA) { off[NA] = P; return; }
    int v = off[i] + bsum[i >> 11];
    off[i] = v;
    cursor[i] = v;
}

// ---- scatter: claim CSR slot, write meta (pair id, j) ----
__global__ __launch_bounds__(256) void scatter_kernel(
    const void* __restrict__ pl, const int* __restrict__ flag,
    int* __restrict__ cursor, int2* __restrict__ meta, int P)
{
    int p = blockIdx.x * 256 + threadIdx.x;
    if (p >= P) return;
    int i, j;
    if (*flag) {
        const long long* q = (const long long*)pl;
        i = (int)q[p]; j = (int)q[(size_t)P + p];
    } else {
        const int* q = (const int*)pl;
        i = q[p]; j = q[(size_t)P + p];
    }
    int pos = atomicAdd(&cursor[i], 1);
    meta[pos] = make_int2(p, j);
}

// ---- MFMA fused pair pipeline (v14): pure streaming — coalesced xs[p] stores ----
template <bool ATOMIC>
__global__ __launch_bounds__(256, 4) void pair_kernel(
    const float* __restrict__ f_ij, const float* __restrict__ rcut,
    const void* __restrict__ pl, const int* __restrict__ flag,
    const unsigned short* __restrict__ w1p, const float* __restrict__ b1,
    const unsigned short* __restrict__ w2p, const float* __restrict__ b2,
    const unsigned short* __restrict__ h, unsigned short* __restrict__ xs,
    float* __restrict__ agg_f32, int P)
{
    __shared__ __align__(16) unsigned short T[256 * 64];
    __shared__ __align__(16) int   ii[256];   // ATOMIC only: atom idx
    __shared__ __align__(16) int   jj[256];   // ATOMIC only: j idx
    __shared__ __align__(16) float rr[256];

    const int tid   = threadIdx.x;
    const int lane  = tid & 63;
    const int wv    = tid >> 6;
    const int g     = lane >> 4;
    const int m     = lane & 15;
    const int pbase = blockIdx.x * 256;
    const int wbase = wv * 64;

    {
        int p = pbase + tid;
        bool valid = (p < P);
        int pc = valid ? p : (P > 0 ? P - 1 : 0);
        rr[tid] = valid ? rcut[pc] : 0.0f;
        if (ATOMIC) {
            long long i_, j_;
            if (*flag) {
                const long long* p64 = (const long long*)pl;
                i_ = p64[pc]; j_ = p64[(size_t)P + pc];
            } else {
                const int* p32 = (const int*)pl;
                i_ = p32[pc]; j_ = p32[(size_t)P + pc];
            }
            ii[tid] = valid ? (int)i_ : 0;
            jj[tid] = valid ? (int)j_ : 0;
        }
    }

    bf16x8 w1f[4], w2f[2][4];
    #pragma unroll
    for (int ct = 0; ct < 4; ++ct)
        w1f[ct] = *(const bf16x8*)&w1p[(ct * 64 + lane) * 8];
    #pragma unroll
    for (int kh = 0; kh < 2; ++kh)
        #pragma unroll
        for (int ct = 0; ct < 4; ++ct)
            w2f[kh][ct] = *(const bf16x8*)&w2p[((kh * 4 + ct) * 64 + lane) * 8];

    float4 b1v[4], b2v[4];
    #pragma unroll
    for (int ft = 0; ft < 4; ++ft) {
        b1v[ft] = *(const float4*)&b1[ft * 16 + g * 4];
        b2v[ft] = *(const float4*)&b2[ft * 16 + g * 4];
    }

    // stage 1 (swapped): C1[ft][pt] = W1^T x f_ij^T
    bf16x8 fijf[4];
    #pragma unroll
    for (int pt = 0; pt < 4; ++pt) {
        int row = pbase + wbase + pt * 16 + m;
        if (row >= P) row = (P > 0 ? P - 1 : 0);
        const float* srcp = f_ij + (size_t)row * R_ + g * 8;
        float4 f0 = *(const float4*)srcp;
        float4 f1 = *(const float4*)(srcp + 4);
        uint4 pk;
        pk.x = pkbf(f0.x, f0.y);
        pk.y = pkbf(f0.z, f0.w);
        pk.z = pkbf(f1.x, f1.y);
        pk.w = pkbf(f1.z, f1.w);
        bf16x8 av; __builtin_memcpy(&av, &pk, 16);
        fijf[pt] = av;
    }
    f32x4 C1[4][4];
    #pragma unroll
    for (int ft = 0; ft < 4; ++ft)
        #pragma unroll
        for (int pt = 0; pt < 4; ++pt) {
            f32x4 z = {0.f, 0.f, 0.f, 0.f};
            C1[ft][pt] = __builtin_amdgcn_mfma_f32_16x16x32_bf16(w1f[ft], fijf[pt], z, 0, 0, 0);
        }

    // ssp + packed-bf16 -> swizzled T
    #pragma unroll
    for (int ft = 0; ft < 4; ++ft)
        #pragma unroll
        for (int pt = 0; pt < 4; ++pt) {
            int wp = pt * 16 + m;
            float v0 = sspf(C1[ft][pt][0] + b1v[ft].x);
            float v1 = sspf(C1[ft][pt][1] + b1v[ft].y);
            float v2 = sspf(C1[ft][pt][2] + b1v[ft].z);
            float v3 = sspf(C1[ft][pt][3] + b1v[ft].w);
            uint2 tw;
            tw.x = pkbf(v0, v1);
            tw.y = pkbf(v2, v3);
            int c = (ft * 4 + g) ^ ((wp & 7) << 1);
            *(uint2*)&T[(wbase + wp) * 64 + c * 4] = tw;
        }

    // ---- stage 2 + epilogue per pt ----
    #pragma unroll
    for (int pt = 0; pt < 4; ++pt) {
        int wpr = pt * 16 + m;
        int s = wpr & 7;
        const unsigned short* Trow = &T[(wbase + wpr) * 64];
        bf16x8 t0 = *(const bf16x8*)&Trow[((0 + g) ^ s) * 8];
        bf16x8 t1 = *(const bf16x8*)&Trow[((4 + g) ^ s) * 8];
        f32x4 C2f[4];
        #pragma unroll
        for (int ft = 0; ft < 4; ++ft) {
            f32x4 c = {0.f, 0.f, 0.f, 0.f};
            c = __builtin_amdgcn_mfma_f32_16x16x32_bf16(w2f[0][ft], t0, c, 0, 0, 0);
            c = __builtin_amdgcn_mfma_f32_16x16x32_bf16(w2f[1][ft], t1, c, 0, 0, 0);
            C2f[ft] = c;
        }

        int pp = wbase + pt * 16 + m;
        int p  = pbase + pp;
        float rc = rr[pp];
        if (!ATOMIC) {
            if (p < P) {
                unsigned short* xrow = xs + (size_t)p * F_;   // PAIR order: coalesced
                #pragma unroll
                for (int ft = 0; ft < 4; ++ft) {
                    int f0 = ft * 16 + g * 4;
                    float x0 = (C2f[ft][0] + b2v[ft].x) * rc;
                    float x1 = (C2f[ft][1] + b2v[ft].y) * rc;
                    float x2 = (C2f[ft][2] + b2v[ft].z) * rc;
                    float x3 = (C2f[ft][3] + b2v[ft].w) * rc;
                    uint2 w;
                    w.x = pkh(x0, x1);
                    w.y = pkh(x2, x3);
                    *(uint2*)&xrow[f0] = w;
                }
            }
        } else {
            int j_ = jj[pp];
            const unsigned short* hrow = h + (size_t)j_ * F_;
            float* aggrow = agg_f32 + (size_t)ii[pp] * F_;
            #pragma unroll
            for (int ft = 0; ft < 4; ++ft) {
                int f0 = ft * 16 + g * 4;
                ushort4 hv = *(const ushort4*)&hrow[f0];
                atomicAdd(aggrow + f0 + 0, (C2f[ft][0] + b2v[ft].x) * rc * bfbits2f(hv.x));
                atomicAdd(aggrow + f0 + 1, (C2f[ft][1] + b2v[ft].y) * rc * bfbits2f(hv.y));
                atomicAdd(aggrow + f0 + 2, (C2f[ft][2] + b2v[ft].z) * rc * bfbits2f(hv.z));
                atomicAdd(aggrow + f0 + 3, (C2f[ft][3] + b2v[ft].w) * rc * bfbits2f(hv.w));
            }
        }
    }
}

// ---- segment-sum with h modulation: wave per atom, lane = feature ----
// acc += xs[meta[k].x][lane] * h[meta[k].y][lane]; fp32 accumulate, bf16 out.
__global__ __launch_bounds__(256) void reduce_kernel(
    const unsigned short* __restrict__ xs, const int2* __restrict__ meta,
    const int* __restrict__ off, const unsigned short* __restrict__ h,
    unsigned short* __restrict__ aggb, int NA)
{
    int a = blockIdx.x * 4 + (threadIdx.x >> 6);
    int lane = threadIdx.x & 63;
    if (a >= NA) return;
    int s = off[a], e = off[a + 1];
    float a0 = 0.f, a1 = 0.f, a2 = 0.f, a3 = 0.f;
    int k = s;
    for (; k + 4 <= e; k += 4) {
        int2 m0 = meta[k + 0], m1 = meta[k + 1];
        int2 m2 = meta[k + 2], m3 = meta[k + 3];
        float w0 = h16f(xs[(size_t)m0.x * F_ + lane]);
        float w1 = h16f(xs[(size_t)m1.x * F_ + lane]);
        float w2 = h16f(xs[(size_t)m2.x * F_ + lane]);
        float w3 = h16f(xs[(size_t)m3.x * F_ + lane]);
        float h0 = bfbits2f(h[(size_t)m0.y * F_ + lane]);
        float h1 = bfbits2f(h[(size_t)m1.y * F_ + lane]);
        float h2 = bfbits2f(h[(size_t)m2.y * F_ + lane]);
        float h3 = bfbits2f(h[(size_t)m3.y * F_ + lane]);
        a0 = fmaf(w0, h0, a0);
        a1 = fmaf(w1, h1, a1);
        a2 = fmaf(w2, h2, a2);
        a3 = fmaf(w3, h3, a3);
    }
    for (; k < e; ++k) {
        int2 mk = meta[k];
        a0 = fmaf(h16f(xs[(size_t)mk.x * F_ + lane]),
                  bfbits2f(h[(size_t)mk.y * F_ + lane]), a0);
    }
    aggb[(size_t)a * F_ + lane] = (unsigned short)f2bf((a0 + a1) + (a2 + a3));
}

// ---- fused output head: out = ssp(agg@w_o1+b_o1)@w_o2+b_o2; u stays in LDS ----
template <bool AGGB>
__global__ __launch_bounds__(256) void out12_kernel(
    const void* __restrict__ agg_p,
    const unsigned short* __restrict__ wo1p, const float* __restrict__ b_o1,
    const unsigned short* __restrict__ wo2p, const float* __restrict__ b_o2,
    float* __restrict__ out, int NA)
{
    __shared__ __align__(16) unsigned short U[4][64][136];   // pad 136: 2-way banks

    const int tid  = threadIdx.x;
    const int lane = tid & 63;
    const int wv   = tid >> 6;
    const int g    = lane >> 4;
    const int m    = lane & 15;
    const int rbase = blockIdx.x * 256 + wv * 64;

    // step 1 (swapped MFMA): u[feat][row] tiles; lane holds 4 consecutive feats
    {
        bf16x8 wf[2][2][4];  // [ch][kh][ct]
        #pragma unroll
        for (int ch = 0; ch < 2; ++ch)
            #pragma unroll
            for (int kh = 0; kh < 2; ++kh)
                #pragma unroll
                for (int ct = 0; ct < 4; ++ct)
                    wf[ch][kh][ct] = *(const bf16x8*)&wo1p[(((ch * 2 + kh) * 4 + ct) * 64 + lane) * 8];
        float4 bo1[2][4];
        #pragma unroll
        for (int ch = 0; ch < 2; ++ch)
            #pragma unroll
            for (int ct = 0; ct < 4; ++ct)
                bo1[ch][ct] = *(const float4*)&b_o1[ch * 64 + ct * 16 + g * 4];

        #pragma unroll
        for (int rt = 0; rt < 4; ++rt) {
            int row = rbase + rt * 16 + m;
            if (row >= NA) row = NA - 1;
            bf16x8 af[2];
            #pragma unroll
            for (int kh = 0; kh < 2; ++kh) {
                if (AGGB) {
                    af[kh] = *(const bf16x8*)((const unsigned short*)agg_p + (size_t)row * F_ + kh * 32 + g * 8);
                } else {
                    const float* ar = (const float*)agg_p + (size_t)row * F_ + kh * 32 + g * 8;
                    float4 v0 = *(const float4*)ar;
                    float4 v1 = *(const float4*)(ar + 4);
                    uint4 pk;
                    pk.x = pkbf(v0.x, v0.y); pk.y = pkbf(v0.z, v0.w);
                    pk.z = pkbf(v1.x, v1.y); pk.w = pkbf(v1.z, v1.w);
                    bf16x8 av; __builtin_memcpy(&av, &pk, 16);
                    af[kh] = av;
                }
            }
            #pragma unroll
            for (int ch = 0; ch < 2; ++ch)
                #pragma unroll
                for (int ct = 0; ct < 4; ++ct) {
                    f32x4 c = {0.f, 0.f, 0.f, 0.f};
                    c = __builtin_amdgcn_mfma_f32_16x16x32_bf16(wf[ch][0][ct], af[0], c, 0, 0, 0);
                    c = __builtin_amdgcn_mfma_f32_16x16x32_bf16(wf[ch][1][ct], af[1], c, 0, 0, 0);
                    float u0 = sspf(c[0] + bo1[ch][ct].x);
                    float u1 = sspf(c[1] + bo1[ch][ct].y);
                    float u2 = sspf(c[2] + bo1[ch][ct].z);
                    float u3 = sspf(c[3] + bo1[ch][ct].w);
                    uint2 uw;
                    uw.x = pkbf(u0, u1);
                    uw.y = pkbf(u2, u3);
                    *(uint2*)&U[wv][rt * 16 + m][ch * 64 + ct * 16 + g * 4] = uw;
                }
        }
    }
    // same-wave LDS visibility (each wave touches only U[wv]) — no barrier needed

    // step 2: out rows = U @ w_o2 + b_o2
    #pragma unroll
    for (int ch = 0; ch < 2; ++ch) {
        bf16x8 wf2[4][4];
        #pragma unroll
        for (int kh = 0; kh < 4; ++kh)
            #pragma unroll
            for (int ct = 0; ct < 4; ++ct)
                wf2[kh][ct] = *(const bf16x8*)&wo2p[(((ch * 4 + kh) * 4 + ct) * 64 + lane) * 8];
        float bo2[4];
        #pragma unroll
        for (int ct = 0; ct < 4; ++ct) bo2[ct] = b_o2[ch * 64 + ct * 16 + m];

        #pragma unroll
        for (int rt = 0; rt < 4; ++rt) {
            bf16x8 af[4];
            #pragma unroll
            for (int kh = 0; kh < 4; ++kh)
                af[kh] = *(const bf16x8*)&U[wv][rt * 16 + m][kh * 32 + g * 8];
            #pragma unroll
            for (int ct = 0; ct < 4; ++ct) {
                f32x4 c = {0.f, 0.f, 0.f, 0.f};
                #pragma unroll
                for (int kh = 0; kh < 4; ++kh)
                    c = __builtin_amdgcn_mfma_f32_16x16x32_bf16(af[kh], wf2[kh][ct], c, 0, 0, 0);
                #pragma unroll
                for (int r = 0; r < 4; ++r) {
                    int ro = rbase + rt * 16 + g * 4 + r;
                    if (ro < NA)
                        out[(size_t)ro * B_ + ch * 64 + ct * 16 + m] = c[r] + bo2[ct];
                }
            }
        }
    }
}

extern "C" void kernel_launch(void* const* d_in, const int* in_sizes, int n_in,
                              void* d_out, int out_size, void* d_ws, size_t ws_size,
                              hipStream_t stream) {
    const float* x    = (const float*)d_in[0];
    const float* f_ij = (const float*)d_in[1];
    const float* rcut = (const float*)d_in[2];
    const void*  pl   = d_in[3];
    const float* w_in = (const float*)d_in[4];
    const float* b_in = (const float*)d_in[5];
    const float* w_f1 = (const float*)d_in[6];
    const float* b_f1 = (const float*)d_in[7];
    const float* w_f2 = (const float*)d_in[8];
    const float* b_f2 = (const float*)d_in[9];
    const float* w_o1 = (const float*)d_in[10];
    const float* b_o1 = (const float*)d_in[11];
    const float* w_o2 = (const float*)d_in[12];
    const float* b_o2 = (const float*)d_in[13];
    float* out = (float*)d_out;

    int NA = in_sizes[0] / B_;
    int P  = in_sizes[2];
    int nb = (NA + 2047) / 2048;
    int hgrid = (NA + 255) / 256;
    int pgrid = (P + 255) / 256;

    size_t hB    = (size_t)NA * F_ * 2;
    size_t xsB   = (size_t)(P + 256) * F_ * 2;
    size_t agB   = (size_t)NA * F_ * 2;
    size_t histB = (size_t)NA * 4;
    size_t offB  = (size_t)(NA + 1) * 4;
    size_t curB  = (size_t)NA * 4;
    size_t mtB   = (size_t)(P + 256) * 8;
    size_t wAll  = (2048 + 4096 + 8192 + 16384) * 2;
    size_t mainNeed = hB + xsB + agB + histB + offB + curB + mtB + 1024 + wAll + 8192;

    bool CSR = (ws_size >= mainNeed) && (nb <= 256);

    char* ws = (char*)d_ws;
    size_t off_ = 0;
    auto alloc = [&](size_t bytes) { size_t o = off_; off_ = (off_ + bytes + 255) & ~(size_t)255; return o; };

    unsigned short* h_buf = (unsigned short*)(ws + alloc(hB));
    unsigned short* w1p   = (unsigned short*)(ws + alloc(2048 * 2));
    unsigned short* w2p   = (unsigned short*)(ws + alloc(4096 * 2));
    unsigned short* wo1p  = (unsigned short*)(ws + alloc(8192 * 2));
    unsigned short* wo2p  = (unsigned short*)(ws + alloc(16384 * 2));
    int* flag             = (int*)(ws + alloc(256));

    if (CSR) {
        unsigned short* xs   = (unsigned short*)(ws + alloc(xsB));
        unsigned short* aggb = (unsigned short*)(ws + alloc(agB));
        int* hist            = (int*)(ws + alloc(histB));
        int* off             = (int*)(ws + alloc(offB));
        int* cursor          = (int*)(ws + alloc(curB));
        int2* meta           = (int2*)(ws + alloc(mtB));
        int* bsum            = (int*)(ws + alloc(1024));

        (void)hipMemsetAsync(hist, 0, histB, stream);
        front_kernel<<<16 + hgrid + pgrid, 256, 0, stream>>>(
            w_f1, w_f2, w_o1, w_o2, w1p, w2p, wo1p, wo2p,
            pl, flag, P, x, w_in, b_in, h_buf, NA, hist, hgrid);
        scan1_kernel<<<nb, 256, 0, stream>>>(hist, off, bsum, NA);
        scan2_kernel<<<1, 256, 0, stream>>>(bsum, nb);
        scan3_kernel<<<(NA + 1 + 255) / 256, 256, 0, stream>>>(off, cursor, bsum, NA, P);
        scatter_kernel<<<pgrid, 256, 0, stream>>>(pl, flag, cursor, meta, P);
        pair_kernel<false><<<pgrid, 256, 0, stream>>>(
            f_ij, rcut, pl, flag, w1p, b_f1, w2p, b_f2, h_buf, xs, nullptr, P);
        reduce_kernel<<<(NA + 3) / 4, 256, 0, stream>>>(xs, meta, off, h_buf, aggb, NA);
        out12_kernel<true><<<hgrid, 256, 0, stream>>>(aggb, wo1p, b_o1, wo2p, b_o2, out, NA);
    } else {
        float* agg = (float*)(ws + alloc((size_t)NA * F_ * 4));
        (void)hipMemsetAsync(agg, 0, (size_t)NA * F_ * 4, stream);
        front_kernel<<<16 + hgrid, 256, 0, stream>>>(
            w_f1, w_f2, w_o1, w_o2, w1p, w2p, wo1p, wo2p,
            pl, flag, P, x, w_in, b_in, h_buf, NA, nullptr, hgrid);
        pair_kernel<true><<<pgrid, 256, 0, stream>>>(
            f_ij, rcut, pl, flag, w1p, b_f1, w2p, b_f2, h_buf, nullptr, agg, P);
        out12_kernel<false><<<hgrid, 256, 0, stream>>>(agg, wo1p, b_o1, wo2p, b_o2, out, NA);
    }
}

// Round 18
// 426.449 us; speedup vs baseline: 1.1325x; 1.1325x over previous
//
#include <hip/hip_runtime.h>
#include <hip/hip_bf16.h>
#include <hip/hip_fp16.h>

#define B_ 128
#define F_ 64
#define R_ 32

typedef __attribute__((ext_vector_type(8))) __bf16 bf16x8;
typedef __attribute__((ext_vector_type(4))) float f32x4;

#define LN2F 0.6931471805599453f
#define L2EF 1.4426950408889634f

// ssp(x) = max(x,0) + ln2*log2(1+2^(-log2e*|x|)) - ln2   (overflow-safe all x)
__device__ __forceinline__ float sspf(float x) {
    float t = fabsf(x) * (-L2EF);
    float e; asm("v_exp_f32 %0, %1" : "=v"(e) : "v"(t));
    float l; asm("v_log_f32 %0, %1" : "=v"(l) : "v"(1.0f + e));
    return fmaxf(x, 0.0f) + fmaf(LN2F, l, -LN2F);
}
__device__ __forceinline__ float bfbits2f(unsigned int us) { return __uint_as_float(us << 16); }
__device__ __forceinline__ unsigned int f2bf(float f) {
    unsigned int u = __float_as_uint(f);
    return (u + 0x7fffu + ((u >> 16) & 1u)) >> 16;   // RNE
}
__device__ __forceinline__ float h16f(unsigned short s) { return __half2float(__ushort_as_half(s)); }
// packed HW conversions (v_cvt_pk_*): bit-pattern via memcpy (free)
__device__ __forceinline__ unsigned int pkbf(float a, float b) {
    __hip_bfloat162 h = __float22bfloat162_rn(make_float2(a, b));
    unsigned int r; __builtin_memcpy(&r, &h, 4); return r;
}
__device__ __forceinline__ unsigned int pkh(float a, float b) {
    __half2 h = __float22half2_rn(make_float2(a, b));
    unsigned int r; __builtin_memcpy(&r, &h, 4); return r;
}

// ---- front: prepack (blocks 0-14) + detect (15) + h (next hgrid) + hist (rest) ----
__global__ __launch_bounds__(256) void front_kernel(
    const float* __restrict__ w1, const float* __restrict__ w2,
    const float* __restrict__ wo1, const float* __restrict__ wo2,
    unsigned short* __restrict__ w1p, unsigned short* __restrict__ w2p,
    unsigned short* __restrict__ wo1p, unsigned short* __restrict__ wo2p,
    const void* __restrict__ pl, int* __restrict__ flag, int P,
    const float* __restrict__ x, const float* __restrict__ w_in,
    const float* __restrict__ b_in, unsigned short* __restrict__ h, int NA,
    int* __restrict__ hist, int hgrid)
{
    int b = blockIdx.x;
    if (b < 15) {
        int t = b * 256 + threadIdx.x;
        if (t < 256) {
            int ct = t >> 6, l = t & 63, g = l >> 4, m = l & 15;
            #pragma unroll
            for (int i = 0; i < 8; ++i)
                w1p[t * 8 + i] = (unsigned short)f2bf(w1[(g * 8 + i) * F_ + ct * 16 + m]);
        } else if (t < 768) {
            int q = t - 256;
            int kh = q >> 8, ct = (q >> 6) & 3, l = q & 63, g = l >> 4, m = l & 15;
            #pragma unroll
            for (int i = 0; i < 8; ++i)
                w2p[q * 8 + i] = (unsigned short)f2bf(w2[(kh * 32 + g * 8 + i) * F_ + ct * 16 + m]);
        } else if (t < 2816) {
            int q = t - 768;
            int l = q & 63, ct = (q >> 6) & 3, kh = (q >> 8) & 3, ch = q >> 10;
            int g = l >> 4, m = l & 15;
            #pragma unroll
            for (int i = 0; i < 8; ++i)
                wo2p[q * 8 + i] = (unsigned short)f2bf(wo2[(kh * 32 + g * 8 + i) * B_ + ch * 64 + ct * 16 + m]);
        } else if (t < 3840) {
            int q = t - 2816;
            int l = q & 63, ct = (q >> 6) & 3, kh = (q >> 8) & 1, ch = q >> 9;
            int g = l >> 4, m = l & 15;
            #pragma unroll
            for (int i = 0; i < 8; ++i)
                wo1p[q * 8 + i] = (unsigned short)f2bf(wo1[(kh * 32 + g * 8 + i) * B_ + ch * 64 + ct * 16 + m]);
        }
        return;
    }
    if (b == 15) {
        if (threadIdx.x < 64) {
            int n = (P < 64) ? P : 64;
            const long long* p64 = (const long long*)pl;
            bool bad = false;
            if ((int)threadIdx.x < n) {
                long long v = p64[threadIdx.x];
                bad = (v < 0) || (v >= 100000000LL);
            }
            unsigned long long bl = __ballot(bad);
            if (threadIdx.x == 0) *flag = (bl == 0ULL) ? 1 : 0;
        }
        return;
    }
    if (b < 16 + hgrid) {
        // h = x @ w_in + b_in, bf16
        int n = (b - 16) * 256 + threadIdx.x;
        if (n >= NA) return;
        float acc[F_];
        #pragma unroll
        for (int f = 0; f < F_; ++f) acc[f] = b_in[f];
        const float4* xrow = (const float4*)(x + (size_t)n * B_);
        #pragma unroll 2
        for (int rb = 0; rb < B_ / 4; ++rb) {
            float4 xv = xrow[rb];
            const float* w0 = w_in + (size_t)(4 * rb) * F_;
            #pragma unroll
            for (int f = 0; f < F_; ++f) acc[f] = fmaf(xv.x, w0[f], acc[f]);
            #pragma unroll
            for (int f = 0; f < F_; ++f) acc[f] = fmaf(xv.y, w0[F_ + f], acc[f]);
            #pragma unroll
            for (int f = 0; f < F_; ++f) acc[f] = fmaf(xv.z, w0[2 * F_ + f], acc[f]);
            #pragma unroll
            for (int f = 0; f < F_; ++f) acc[f] = fmaf(xv.w, w0[3 * F_ + f], acc[f]);
        }
        uint4* hrow = (uint4*)(h + (size_t)n * F_);
        #pragma unroll
        for (int q = 0; q < F_ / 8; ++q) {
            uint4 ob;
            ob.x = pkbf(acc[8 * q + 0], acc[8 * q + 1]);
            ob.y = pkbf(acc[8 * q + 2], acc[8 * q + 3]);
            ob.z = pkbf(acc[8 * q + 4], acc[8 * q + 5]);
            ob.w = pkbf(acc[8 * q + 6], acc[8 * q + 7]);
            hrow[q] = ob;
        }
        return;
    }
    // hist blocks: block-local dtype detect
    __shared__ int sflag;
    if (threadIdx.x < 64) {
        int n = (P < 64) ? P : 64;
        const long long* p64 = (const long long*)pl;
        bool bad = false;
        if ((int)threadIdx.x < n) {
            long long v = p64[threadIdx.x];
            bad = (v < 0) || (v >= 100000000LL);
        }
        unsigned long long bl = __ballot(bad);
        if (threadIdx.x == 0) sflag = (bl == 0ULL) ? 1 : 0;
    }
    __syncthreads();
    int p = (b - 16 - hgrid) * 256 + threadIdx.x;
    if (p >= P) return;
    int i = sflag ? (int)((const long long*)pl)[p] : ((const int*)pl)[p];
    atomicAdd(&hist[i], 1);
}

// ---- hierarchical scan, level 1 ----
__global__ __launch_bounds__(256) void scan1_kernel(
    const int* __restrict__ hist, int* __restrict__ off,
    int* __restrict__ bsum, int NA)
{
    __shared__ int s[256];
    int t = threadIdx.x;
    int idx = blockIdx.x * 2048 + t * 8;
    int v[8];
    int run = 0;
    #pragma unroll
    for (int k = 0; k < 8; ++k) {
        int i = idx + k;
        int c = (i < NA) ? hist[i] : 0;
        v[k] = run; run += c;
    }
    s[t] = run;
    __syncthreads();
    for (int o = 1; o < 256; o <<= 1) {
        int x = (t >= o) ? s[t - o] : 0;
        __syncthreads();
        s[t] += x;
        __syncthreads();
    }
    int base = (t == 0) ? 0 : s[t - 1];
    #pragma unroll
    for (int k = 0; k < 8; ++k) {
        int i = idx + k;
        if (i < NA) off[i] = v[k] + base;
    }
    if (t == 255) bsum[blockIdx.x] = s[255];
}

__global__ __launch_bounds__(256) void scan2_kernel(int* __restrict__ bsum, int nb) {
    __shared__ int s[256];
    int t = threadIdx.x;
    int v = (t < nb) ? bsum[t] : 0;
    s[t] = v;
    __syncthreads();
    for (int o = 1; o < 256; o <<= 1) {
        int x = (t >= o) ? s[t - o] : 0;
        __syncthreads();
        s[t] += x;
        __syncthreads();
    }
    if (t < nb) bsum[t] = s[t] - v;
}

__global__ __launch_bounds__(256) void scan3_kernel(
    int* __restrict__ off, int* __restrict__ cursor,
    const int* __restrict__ bsum, int NA, int P)
{
    int i = blockIdx.x * 256 + threadIdx.x;
    if (i > NA) return;
    if (i == NA) { off[NA] = P; return; }
    int v = off[i] + bsum[i >> 11];
    off[i] = v;
    cursor[i] = v;
}

// ---- MFMA fused pair pipeline (v15): coalesced xs[p] stores + inline CSR claim ----
// CSR: phase 0 claims slot + writes meta[pos]=(p,j) (overlapped by MFMA pipeline);
// epilogue stores wij*rc to xs[p] in PAIR order (fully coalesced).
template <bool ATOMIC>
__global__ __launch_bounds__(256, 4) void pair_kernel(
    const float* __restrict__ f_ij, const float* __restrict__ rcut,
    const void* __restrict__ pl, const int* __restrict__ flag,
    const unsigned short* __restrict__ w1p, const float* __restrict__ b1,
    const unsigned short* __restrict__ w2p, const float* __restrict__ b2,
    const unsigned short* __restrict__ h, unsigned short* __restrict__ xs,
    int* __restrict__ cursor, int2* __restrict__ meta,
    float* __restrict__ agg_f32, int P)
{
    __shared__ __align__(16) unsigned short T[256 * 64];
    __shared__ __align__(16) int   ii[256];   // ATOMIC only: atom idx
    __shared__ __align__(16) int   jj[256];   // ATOMIC only: j idx
    __shared__ __align__(16) float rr[256];

    const int tid   = threadIdx.x;
    const int lane  = tid & 63;
    const int wv    = tid >> 6;
    const int g     = lane >> 4;
    const int m     = lane & 15;
    const int pbase = blockIdx.x * 256;
    const int wbase = wv * 64;

    {
        int p = pbase + tid;
        bool valid = (p < P);
        int pc = valid ? p : (P > 0 ? P - 1 : 0);
        rr[tid] = valid ? rcut[pc] : 0.0f;
        long long i_, j_;
        if (*flag) {
            const long long* p64 = (const long long*)pl;
            i_ = p64[pc]; j_ = p64[(size_t)P + pc];
        } else {
            const int* p32 = (const int*)pl;
            i_ = p32[pc]; j_ = p32[(size_t)P + pc];
        }
        if (ATOMIC) {
            ii[tid] = valid ? (int)i_ : 0;
            jj[tid] = valid ? (int)j_ : 0;
        } else if (valid) {
            int pos = atomicAdd(&cursor[(int)i_], 1);
            meta[pos] = make_int2(p, (int)j_);     // overlapped by compute below
        }
    }

    bf16x8 w1f[4], w2f[2][4];
    #pragma unroll
    for (int ct = 0; ct < 4; ++ct)
        w1f[ct] = *(const bf16x8*)&w1p[(ct * 64 + lane) * 8];
    #pragma unroll
    for (int kh = 0; kh < 2; ++kh)
        #pragma unroll
        for (int ct = 0; ct < 4; ++ct)
            w2f[kh][ct] = *(const bf16x8*)&w2p[((kh * 4 + ct) * 64 + lane) * 8];

    float4 b1v[4], b2v[4];
    #pragma unroll
    for (int ft = 0; ft < 4; ++ft) {
        b1v[ft] = *(const float4*)&b1[ft * 16 + g * 4];
        b2v[ft] = *(const float4*)&b2[ft * 16 + g * 4];
    }

    // stage 1 (swapped): C1[ft][pt] = W1^T x f_ij^T
    bf16x8 fijf[4];
    #pragma unroll
    for (int pt = 0; pt < 4; ++pt) {
        int row = pbase + wbase + pt * 16 + m;
        if (row >= P) row = (P > 0 ? P - 1 : 0);
        const float* srcp = f_ij + (size_t)row * R_ + g * 8;
        float4 f0 = *(const float4*)srcp;
        float4 f1 = *(const float4*)(srcp + 4);
        uint4 pk;
        pk.x = pkbf(f0.x, f0.y);
        pk.y = pkbf(f0.z, f0.w);
        pk.z = pkbf(f1.x, f1.y);
        pk.w = pkbf(f1.z, f1.w);
        bf16x8 av; __builtin_memcpy(&av, &pk, 16);
        fijf[pt] = av;
    }
    f32x4 C1[4][4];
    #pragma unroll
    for (int ft = 0; ft < 4; ++ft)
        #pragma unroll
        for (int pt = 0; pt < 4; ++pt) {
            f32x4 z = {0.f, 0.f, 0.f, 0.f};
            C1[ft][pt] = __builtin_amdgcn_mfma_f32_16x16x32_bf16(w1f[ft], fijf[pt], z, 0, 0, 0);
        }

    // ssp + packed-bf16 -> swizzled T
    #pragma unroll
    for (int ft = 0; ft < 4; ++ft)
        #pragma unroll
        for (int pt = 0; pt < 4; ++pt) {
            int wp = pt * 16 + m;
            float v0 = sspf(C1[ft][pt][0] + b1v[ft].x);
            float v1 = sspf(C1[ft][pt][1] + b1v[ft].y);
            float v2 = sspf(C1[ft][pt][2] + b1v[ft].z);
            float v3 = sspf(C1[ft][pt][3] + b1v[ft].w);
            uint2 tw;
            tw.x = pkbf(v0, v1);
            tw.y = pkbf(v2, v3);
            int c = (ft * 4 + g) ^ ((wp & 7) << 1);
            *(uint2*)&T[(wbase + wp) * 64 + c * 4] = tw;
        }

    // ---- stage 2 + epilogue per pt ----
    #pragma unroll
    for (int pt = 0; pt < 4; ++pt) {
        int wpr = pt * 16 + m;
        int s = wpr & 7;
        const unsigned short* Trow = &T[(wbase + wpr) * 64];
        bf16x8 t0 = *(const bf16x8*)&Trow[((0 + g) ^ s) * 8];
        bf16x8 t1 = *(const bf16x8*)&Trow[((4 + g) ^ s) * 8];
        f32x4 C2f[4];
        #pragma unroll
        for (int ft = 0; ft < 4; ++ft) {
            f32x4 c = {0.f, 0.f, 0.f, 0.f};
            c = __builtin_amdgcn_mfma_f32_16x16x32_bf16(w2f[0][ft], t0, c, 0, 0, 0);
            c = __builtin_amdgcn_mfma_f32_16x16x32_bf16(w2f[1][ft], t1, c, 0, 0, 0);
            C2f[ft] = c;
        }

        int pp = wbase + pt * 16 + m;
        int p  = pbase + pp;
        float rc = rr[pp];
        if (!ATOMIC) {
            if (p < P) {
                unsigned short* xrow = xs + (size_t)p * F_;   // PAIR order: coalesced
                #pragma unroll
                for (int ft = 0; ft < 4; ++ft) {
                    int f0 = ft * 16 + g * 4;
                    float x0 = (C2f[ft][0] + b2v[ft].x) * rc;
                    float x1 = (C2f[ft][1] + b2v[ft].y) * rc;
                    float x2 = (C2f[ft][2] + b2v[ft].z) * rc;
                    float x3 = (C2f[ft][3] + b2v[ft].w) * rc;
                    uint2 w;
                    w.x = pkh(x0, x1);
                    w.y = pkh(x2, x3);
                    *(uint2*)&xrow[f0] = w;
                }
            }
        } else {
            int j_ = jj[pp];
            const unsigned short* hrow = h + (size_t)j_ * F_;
            float* aggrow = agg_f32 + (size_t)ii[pp] * F_;
            #pragma unroll
            for (int ft = 0; ft < 4; ++ft) {
                int f0 = ft * 16 + g * 4;
                ushort4 hv = *(const ushort4*)&hrow[f0];
                atomicAdd(aggrow + f0 + 0, (C2f[ft][0] + b2v[ft].x) * rc * bfbits2f(hv.x));
                atomicAdd(aggrow + f0 + 1, (C2f[ft][1] + b2v[ft].y) * rc * bfbits2f(hv.y));
                atomicAdd(aggrow + f0 + 2, (C2f[ft][2] + b2v[ft].z) * rc * bfbits2f(hv.z));
                atomicAdd(aggrow + f0 + 3, (C2f[ft][3] + b2v[ft].w) * rc * bfbits2f(hv.w));
            }
        }
    }
}

// ---- segment-sum with h modulation: wave per atom, lane = feature ----
// acc += xs[meta[k].x][lane] * h[meta[k].y][lane]; fp32 accumulate, bf16 out.
__global__ __launch_bounds__(256) void reduce_kernel(
    const unsigned short* __restrict__ xs, const int2* __restrict__ meta,
    const int* __restrict__ off, const unsigned short* __restrict__ h,
    unsigned short* __restrict__ aggb, int NA)
{
    int a = blockIdx.x * 4 + (threadIdx.x >> 6);
    int lane = threadIdx.x & 63;
    if (a >= NA) return;
    int s = off[a], e = off[a + 1];
    float a0 = 0.f, a1 = 0.f, a2 = 0.f, a3 = 0.f;
    int k = s;
    for (; k + 4 <= e; k += 4) {
        int2 m0 = meta[k + 0], m1 = meta[k + 1];
        int2 m2 = meta[k + 2], m3 = meta[k + 3];
        float w0 = h16f(xs[(size_t)m0.x * F_ + lane]);
        float w1 = h16f(xs[(size_t)m1.x * F_ + lane]);
        float w2 = h16f(xs[(size_t)m2.x * F_ + lane]);
        float w3 = h16f(xs[(size_t)m3.x * F_ + lane]);
        float h0 = bfbits2f(h[(size_t)m0.y * F_ + lane]);
        float h1 = bfbits2f(h[(size_t)m1.y * F_ + lane]);
        float h2 = bfbits2f(h[(size_t)m2.y * F_ + lane]);
        float h3 = bfbits2f(h[(size_t)m3.y * F_ + lane]);
        a0 = fmaf(w0, h0, a0);
        a1 = fmaf(w1, h1, a1);
        a2 = fmaf(w2, h2, a2);
        a3 = fmaf(w3, h3, a3);
    }
    for (; k < e; ++k) {
        int2 mk = meta[k];
        a0 = fmaf(h16f(xs[(size_t)mk.x * F_ + lane]),
                  bfbits2f(h[(size_t)mk.y * F_ + lane]), a0);
    }
    aggb[(size_t)a * F_ + lane] = (unsigned short)f2bf((a0 + a1) + (a2 + a3));
}

// ---- fused output head: out = ssp(agg@w_o1+b_o1)@w_o2+b_o2; u stays in LDS ----
template <bool AGGB>
__global__ __launch_bounds__(256) void out12_kernel(
    const void* __restrict__ agg_p,
    const unsigned short* __restrict__ wo1p, const float* __restrict__ b_o1,
    const unsigned short* __restrict__ wo2p, const float* __restrict__ b_o2,
    float* __restrict__ out, int NA)
{
    __shared__ __align__(16) unsigned short U[4][64][136];   // pad 136: 2-way banks

    const int tid  = threadIdx.x;
    const int lane = tid & 63;
    const int wv   = tid >> 6;
    const int g    = lane >> 4;
    const int m    = lane & 15;
    const int rbase = blockIdx.x * 256 + wv * 64;

    // step 1 (swapped MFMA): u[feat][row] tiles; lane holds 4 consecutive feats
    {
        bf16x8 wf[2][2][4];  // [ch][kh][ct]
        #pragma unroll
        for (int ch = 0; ch < 2; ++ch)
            #pragma unroll
            for (int kh = 0; kh < 2; ++kh)
                #pragma unroll
                for (int ct = 0; ct < 4; ++ct)
                    wf[ch][kh][ct] = *(const bf16x8*)&wo1p[(((ch * 2 + kh) * 4 + ct) * 64 + lane) * 8];
        float4 bo1[2][4];
        #pragma unroll
        for (int ch = 0; ch < 2; ++ch)
            #pragma unroll
            for (int ct = 0; ct < 4; ++ct)
                bo1[ch][ct] = *(const float4*)&b_o1[ch * 64 + ct * 16 + g * 4];

        #pragma unroll
        for (int rt = 0; rt < 4; ++rt) {
            int row = rbase + rt * 16 + m;
            if (row >= NA) row = NA - 1;
            bf16x8 af[2];
            #pragma unroll
            for (int kh = 0; kh < 2; ++kh) {
                if (AGGB) {
                    af[kh] = *(const bf16x8*)((const unsigned short*)agg_p + (size_t)row * F_ + kh * 32 + g * 8);
                } else {
                    const float* ar = (const float*)agg_p + (size_t)row * F_ + kh * 32 + g * 8;
                    float4 v0 = *(const float4*)ar;
                    float4 v1 = *(const float4*)(ar + 4);
                    uint4 pk;
                    pk.x = pkbf(v0.x, v0.y); pk.y = pkbf(v0.z, v0.w);
                    pk.z = pkbf(v1.x, v1.y); pk.w = pkbf(v1.z, v1.w);
                    bf16x8 av; __builtin_memcpy(&av, &pk, 16);
                    af[kh] = av;
                }
            }
            #pragma unroll
            for (int ch = 0; ch < 2; ++ch)
                #pragma unroll
                for (int ct = 0; ct < 4; ++ct) {
                    f32x4 c = {0.f, 0.f, 0.f, 0.f};
                    c = __builtin_amdgcn_mfma_f32_16x16x32_bf16(wf[ch][0][ct], af[0], c, 0, 0, 0);
                    c = __builtin_amdgcn_mfma_f32_16x16x32_bf16(wf[ch][1][ct], af[1], c, 0, 0, 0);
                    float u0 = sspf(c[0] + bo1[ch][ct].x);
                    float u1 = sspf(c[1] + bo1[ch][ct].y);
                    float u2 = sspf(c[2] + bo1[ch][ct].z);
                    float u3 = sspf(c[3] + bo1[ch][ct].w);
                    uint2 uw;
                    uw.x = pkbf(u0, u1);
                    uw.y = pkbf(u2, u3);
                    *(uint2*)&U[wv][rt * 16 + m][ch * 64 + ct * 16 + g * 4] = uw;
                }
        }
    }
    // same-wave LDS visibility (each wave touches only U[wv]) — no barrier needed

    // step 2: out rows = U @ w_o2 + b_o2
    #pragma unroll
    for (int ch = 0; ch < 2; ++ch) {
        bf16x8 wf2[4][4];
        #pragma unroll
        for (int kh = 0; kh < 4; ++kh)
            #pragma unroll
            for (int ct = 0; ct < 4; ++ct)
                wf2[kh][ct] = *(const bf16x8*)&wo2p[(((ch * 4 + kh) * 4 + ct) * 64 + lane) * 8];
        float bo2[4];
        #pragma unroll
        for (int ct = 0; ct < 4; ++ct) bo2[ct] = b_o2[ch * 64 + ct * 16 + m];

        #pragma unroll
        for (int rt = 0; rt < 4; ++rt) {
            bf16x8 af[4];
            #pragma unroll
            for (int kh = 0; kh < 4; ++kh)
                af[kh] = *(const bf16x8*)&U[wv][rt * 16 + m][kh * 32 + g * 8];
            #pragma unroll
            for (int ct = 0; ct < 4; ++ct) {
                f32x4 c = {0.f, 0.f, 0.f, 0.f};
                #pragma unroll
                for (int kh = 0; kh < 4; ++kh)
                    c = __builtin_amdgcn_mfma_f32_16x16x32_bf16(af[kh], wf2[kh][ct], c, 0, 0, 0);
                #pragma unroll
                for (int r = 0; r < 4; ++r) {
                    int ro = rbase + rt * 16 + g * 4 + r;
                    if (ro < NA)
                        out[(size_t)ro * B_ + ch * 64 + ct * 16 + m] = c[r] + bo2[ct];
                }
            }
        }
    }
}

extern "C" void kernel_launch(void* const* d_in, const int* in_sizes, int n_in,
                              void* d_out, int out_size, void* d_ws, size_t ws_size,
                              hipStream_t stream) {
    const float* x    = (const float*)d_in[0];
    const float* f_ij = (const float*)d_in[1];
    const float* rcut = (const float*)d_in[2];
    const void*  pl   = d_in[3];
    const float* w_in = (const float*)d_in[4];
    const float* b_in = (const float*)d_in[5];
    const float* w_f1 = (const float*)d_in[6];
    const float* b_f1 = (const float*)d_in[7];
    const float* w_f2 = (const float*)d_in[8];
    const float* b_f2 = (const float*)d_in[9];
    const float* w_o1 = (const float*)d_in[10];
    const float* b_o1 = (const float*)d_in[11];
    const float* w_o2 = (const float*)d_in[12];
    const float* b_o2 = (const float*)d_in[13];
    float* out = (float*)d_out;

    int NA = in_sizes[0] / B_;
    int P  = in_sizes[2];
    int nb = (NA + 2047) / 2048;
    int hgrid = (NA + 255) / 256;
    int pgrid = (P + 255) / 256;

    size_t hB    = (size_t)NA * F_ * 2;
    size_t xsB   = (size_t)(P + 256) * F_ * 2;
    size_t agB   = (size_t)NA * F_ * 2;
    size_t histB = (size_t)NA * 4;
    size_t offB  = (size_t)(NA + 1) * 4;
    size_t curB  = (size_t)NA * 4;
    size_t mtB   = (size_t)(P + 256) * 8;
    size_t wAll  = (2048 + 4096 + 8192 + 16384) * 2;
    size_t mainNeed = hB + xsB + agB + histB + offB + curB + mtB + 1024 + wAll + 8192;

    bool CSR = (ws_size >= mainNeed) && (nb <= 256);

    char* ws = (char*)d_ws;
    size_t off_ = 0;
    auto alloc = [&](size_t bytes) { size_t o = off_; off_ = (off_ + bytes + 255) & ~(size_t)255; return o; };

    unsigned short* h_buf = (unsigned short*)(ws + alloc(hB));
    unsigned short* w1p   = (unsigned short*)(ws + alloc(2048 * 2));
    unsigned short* w2p   = (unsigned short*)(ws + alloc(4096 * 2));
    unsigned short* wo1p  = (unsigned short*)(ws + alloc(8192 * 2));
    unsigned short* wo2p  = (unsigned short*)(ws + alloc(16384 * 2));
    int* flag             = (int*)(ws + alloc(256));

    if (CSR) {
        unsigned short* xs   = (unsigned short*)(ws + alloc(xsB));
        unsigned short* aggb = (unsigned short*)(ws + alloc(agB));
        int* hist            = (int*)(ws + alloc(histB));
        int* off             = (int*)(ws + alloc(offB));
        int* cursor          = (int*)(ws + alloc(curB));
        int2* meta           = (int2*)(ws + alloc(mtB));
        int* bsum            = (int*)(ws + alloc(1024));

        (void)hipMemsetAsync(hist, 0, histB, stream);
        front_kernel<<<16 + hgrid + pgrid, 256, 0, stream>>>(
            w_f1, w_f2, w_o1, w_o2, w1p, w2p, wo1p, wo2p,
            pl, flag, P, x, w_in, b_in, h_buf, NA, hist, hgrid);
        scan1_kernel<<<nb, 256, 0, stream>>>(hist, off, bsum, NA);
        scan2_kernel<<<1, 256, 0, stream>>>(bsum, nb);
        scan3_kernel<<<(NA + 1 + 255) / 256, 256, 0, stream>>>(off, cursor, bsum, NA, P);
        pair_kernel<false><<<pgrid, 256, 0, stream>>>(
            f_ij, rcut, pl, flag, w1p, b_f1, w2p, b_f2, h_buf, xs, cursor, meta, nullptr, P);
        reduce_kernel<<<(NA + 3) / 4, 256, 0, stream>>>(xs, meta, off, h_buf, aggb, NA);
        out12_kernel<true><<<hgrid, 256, 0, stream>>>(aggb, wo1p, b_o1, wo2p, b_o2, out, NA);
    } else {
        float* agg = (float*)(ws + alloc((size_t)NA * F_ * 4));
        (void)hipMemsetAsync(agg, 0, (size_t)NA * F_ * 4, stream);
        front_kernel<<<16 + hgrid, 256, 0, stream>>>(
            w_f1, w_f2, w_o1, w_o2, w1p, w2p, wo1p, wo2p,
            pl, flag, P, x, w_in, b_in, h_buf, NA, nullptr, hgrid);
        pair_kernel<true><<<pgrid, 256, 0, stream>>>(
            f_ij, rcut, pl, flag, w1p, b_f1, w2p, b_f2, h_buf, nullptr, nullptr, nullptr, agg, P);
        out12_kernel<false><<<hgrid, 256, 0, stream>>>(agg, wo1p, b_o1, wo2p, b_o2, out, NA);
    }
}

// Round 19
// 362.563 us; speedup vs baseline: 1.3321x; 1.1762x over previous
//
#include <hip/hip_runtime.h>
#include <hip/hip_bf16.h>
#include <hip/hip_fp16.h>

#define B_ 128
#define F_ 64
#define R_ 32

typedef __attribute__((ext_vector_type(8))) __bf16 bf16x8;
typedef __attribute__((ext_vector_type(4))) float f32x4;

#define LN2F 0.6931471805599453f
#define L2EF 1.4426950408889634f

// ssp(x) = max(x,0) + ln2*log2(1+2^(-log2e*|x|)) - ln2   (overflow-safe all x)
__device__ __forceinline__ float sspf(float x) {
    float t = fabsf(x) * (-L2EF);
    float e; asm("v_exp_f32 %0, %1" : "=v"(e) : "v"(t));
    float l; asm("v_log_f32 %0, %1" : "=v"(l) : "v"(1.0f + e));
    return fmaxf(x, 0.0f) + fmaf(LN2F, l, -LN2F);
}
__device__ __forceinline__ float bfbits2f(unsigned int us) { return __uint_as_float(us << 16); }
__device__ __forceinline__ unsigned int f2bf(float f) {
    unsigned int u = __float_as_uint(f);
    return (u + 0x7fffu + ((u >> 16) & 1u)) >> 16;   // RNE
}
__device__ __forceinline__ float h16f(unsigned short s) { return __half2float(__ushort_as_half(s)); }
// packed HW conversions (v_cvt_pk_*): bit-pattern via memcpy (free)
__device__ __forceinline__ unsigned int pkbf(float a, float b) {
    __hip_bfloat162 h = __float22bfloat162_rn(make_float2(a, b));
    unsigned int r; __builtin_memcpy(&r, &h, 4); return r;
}
__device__ __forceinline__ unsigned int pkh(float a, float b) {
    __half2 h = __float22half2_rn(make_float2(a, b));
    unsigned int r; __builtin_memcpy(&r, &h, 4); return r;
}

// ---- front: prepack (0-14) + detect (15) + h (hgrid) + hist+rank (rest) ----
__global__ __launch_bounds__(256) void front_kernel(
    const float* __restrict__ w1, const float* __restrict__ w2,
    const float* __restrict__ wo1, const float* __restrict__ wo2,
    unsigned short* __restrict__ w1p, unsigned short* __restrict__ w2p,
    unsigned short* __restrict__ wo1p, unsigned short* __restrict__ wo2p,
    const void* __restrict__ pl, int* __restrict__ flag, int P,
    const float* __restrict__ x, const float* __restrict__ w_in,
    const float* __restrict__ b_in, unsigned short* __restrict__ h, int NA,
    int* __restrict__ hist, int* __restrict__ rank, int hgrid)
{
    int b = blockIdx.x;
    if (b < 15) {
        int t = b * 256 + threadIdx.x;
        if (t < 256) {
            int ct = t >> 6, l = t & 63, g = l >> 4, m = l & 15;
            #pragma unroll
            for (int i = 0; i < 8; ++i)
                w1p[t * 8 + i] = (unsigned short)f2bf(w1[(g * 8 + i) * F_ + ct * 16 + m]);
        } else if (t < 768) {
            int q = t - 256;
            int kh = q >> 8, ct = (q >> 6) & 3, l = q & 63, g = l >> 4, m = l & 15;
            #pragma unroll
            for (int i = 0; i < 8; ++i)
                w2p[q * 8 + i] = (unsigned short)f2bf(w2[(kh * 32 + g * 8 + i) * F_ + ct * 16 + m]);
        } else if (t < 2816) {
            int q = t - 768;
            int l = q & 63, ct = (q >> 6) & 3, kh = (q >> 8) & 3, ch = q >> 10;
            int g = l >> 4, m = l & 15;
            #pragma unroll
            for (int i = 0; i < 8; ++i)
                wo2p[q * 8 + i] = (unsigned short)f2bf(wo2[(kh * 32 + g * 8 + i) * B_ + ch * 64 + ct * 16 + m]);
        } else if (t < 3840) {
            int q = t - 2816;
            int l = q & 63, ct = (q >> 6) & 3, kh = (q >> 8) & 1, ch = q >> 9;
            int g = l >> 4, m = l & 15;
            #pragma unroll
            for (int i = 0; i < 8; ++i)
                wo1p[q * 8 + i] = (unsigned short)f2bf(wo1[(kh * 32 + g * 8 + i) * B_ + ch * 64 + ct * 16 + m]);
        }
        return;
    }
    if (b == 15) {
        if (threadIdx.x < 64) {
            int n = (P < 64) ? P : 64;
            const long long* p64 = (const long long*)pl;
            bool bad = false;
            if ((int)threadIdx.x < n) {
                long long v = p64[threadIdx.x];
                bad = (v < 0) || (v >= 100000000LL);
            }
            unsigned long long bl = __ballot(bad);
            if (threadIdx.x == 0) *flag = (bl == 0ULL) ? 1 : 0;
        }
        return;
    }
    if (b < 16 + hgrid) {
        // h = x @ w_in + b_in, bf16
        int n = (b - 16) * 256 + threadIdx.x;
        if (n >= NA) return;
        float acc[F_];
        #pragma unroll
        for (int f = 0; f < F_; ++f) acc[f] = b_in[f];
        const float4* xrow = (const float4*)(x + (size_t)n * B_);
        #pragma unroll 2
        for (int rb = 0; rb < B_ / 4; ++rb) {
            float4 xv = xrow[rb];
            const float* w0 = w_in + (size_t)(4 * rb) * F_;
            #pragma unroll
            for (int f = 0; f < F_; ++f) acc[f] = fmaf(xv.x, w0[f], acc[f]);
            #pragma unroll
            for (int f = 0; f < F_; ++f) acc[f] = fmaf(xv.y, w0[F_ + f], acc[f]);
            #pragma unroll
            for (int f = 0; f < F_; ++f) acc[f] = fmaf(xv.z, w0[2 * F_ + f], acc[f]);
            #pragma unroll
            for (int f = 0; f < F_; ++f) acc[f] = fmaf(xv.w, w0[3 * F_ + f], acc[f]);
        }
        uint4* hrow = (uint4*)(h + (size_t)n * F_);
        #pragma unroll
        for (int q = 0; q < F_ / 8; ++q) {
            uint4 ob;
            ob.x = pkbf(acc[8 * q + 0], acc[8 * q + 1]);
            ob.y = pkbf(acc[8 * q + 2], acc[8 * q + 3]);
            ob.z = pkbf(acc[8 * q + 4], acc[8 * q + 5]);
            ob.w = pkbf(acc[8 * q + 6], acc[8 * q + 7]);
            hrow[q] = ob;
        }
        return;
    }
    // hist blocks: block-local dtype detect; rank[p] = per-atom arrival order
    __shared__ int sflag;
    if (threadIdx.x < 64) {
        int n = (P < 64) ? P : 64;
        const long long* p64 = (const long long*)pl;
        bool bad = false;
        if ((int)threadIdx.x < n) {
            long long v = p64[threadIdx.x];
            bad = (v < 0) || (v >= 100000000LL);
        }
        unsigned long long bl = __ballot(bad);
        if (threadIdx.x == 0) sflag = (bl == 0ULL) ? 1 : 0;
    }
    __syncthreads();
    int p = (b - 16 - hgrid) * 256 + threadIdx.x;
    if (p >= P) return;
    int i = sflag ? (int)((const long long*)pl)[p] : ((const int*)pl)[p];
    rank[p] = atomicAdd(&hist[i], 1);
}

// ---- hierarchical scan, level 1 ----
__global__ __launch_bounds__(256) void scan1_kernel(
    const int* __restrict__ hist, int* __restrict__ off,
    int* __restrict__ bsum, int NA)
{
    __shared__ int s[256];
    int t = threadIdx.x;
    int idx = blockIdx.x * 2048 + t * 8;
    int v[8];
    int run = 0;
    #pragma unroll
    for (int k = 0; k < 8; ++k) {
        int i = idx + k;
        int c = (i < NA) ? hist[i] : 0;
        v[k] = run; run += c;
    }
    s[t] = run;
    __syncthreads();
    for (int o = 1; o < 256; o <<= 1) {
        int x = (t >= o) ? s[t - o] : 0;
        __syncthreads();
        s[t] += x;
        __syncthreads();
    }
    int base = (t == 0) ? 0 : s[t - 1];
    #pragma unroll
    for (int k = 0; k < 8; ++k) {
        int i = idx + k;
        if (i < NA) off[i] = v[k] + base;
    }
    if (t == 255) bsum[blockIdx.x] = s[255];
}

__global__ __launch_bounds__(256) void scan2_kernel(int* __restrict__ bsum, int nb) {
    __shared__ int s[256];
    int t = threadIdx.x;
    int v = (t < nb) ? bsum[t] : 0;
    s[t] = v;
    __syncthreads();
    for (int o = 1; o < 256; o <<= 1) {
        int x = (t >= o) ? s[t - o] : 0;
        __syncthreads();
        s[t] += x;
        __syncthreads();
    }
    if (t < nb) bsum[t] = s[t] - v;
}

__global__ __launch_bounds__(256) void scan3_kernel(
    int* __restrict__ off, const int* __restrict__ bsum, int NA, int P)
{
    int i = blockIdx.x * 256 + threadIdx.x;
    if (i > NA) return;
    if (i == NA) { off[NA] = P; return; }
    off[i] += bsum[i >> 11];
}

// ---- MFMA fused pair pipeline (v16): deterministic CSR slot (off+rank), ----
// rolling h-prefetch, modulated scattered xs[pos] store. NO contended atomics.
template <bool ATOMIC>
__global__ __launch_bounds__(256, 4) void pair_kernel(
    const float* __restrict__ f_ij, const float* __restrict__ rcut,
    const void* __restrict__ pl, const int* __restrict__ flag,
    const unsigned short* __restrict__ w1p, const float* __restrict__ b1,
    const unsigned short* __restrict__ w2p, const float* __restrict__ b2,
    const unsigned short* __restrict__ h, unsigned short* __restrict__ xs,
    const int* __restrict__ rank, const int* __restrict__ off,
    float* __restrict__ agg_f32, int P)
{
    __shared__ __align__(16) unsigned short T[256 * 64];
    __shared__ __align__(16) int   ii[256];   // ATOMIC: atom idx; CSR: slot pos
    __shared__ __align__(16) int   jj[256];
    __shared__ __align__(16) float rr[256];

    const int tid   = threadIdx.x;
    const int lane  = tid & 63;
    const int wv    = tid >> 6;
    const int g     = lane >> 4;
    const int m     = lane & 15;
    const int pbase = blockIdx.x * 256;
    const int wbase = wv * 64;

    {
        int p = pbase + tid;
        bool valid = (p < P);
        int pc = valid ? p : (P > 0 ? P - 1 : 0);
        long long i_, j_;
        if (*flag) {
            const long long* p64 = (const long long*)pl;
            i_ = p64[pc]; j_ = p64[(size_t)P + pc];
        } else {
            const int* p32 = (const int*)pl;
            i_ = p32[pc]; j_ = p32[(size_t)P + pc];
        }
        jj[tid] = valid ? (int)j_ : 0;
        rr[tid] = valid ? rcut[pc] : 0.0f;
        if (ATOMIC) {
            ii[tid] = valid ? (int)i_ : 0;
        } else {
            // deterministic CSR slot: off[i] + rank[p]  (no contended atomic)
            ii[tid] = valid ? (off[(int)i_] + rank[pc]) : (P + tid);
        }
    }

    bf16x8 w1f[4], w2f[2][4];
    #pragma unroll
    for (int ct = 0; ct < 4; ++ct)
        w1f[ct] = *(const bf16x8*)&w1p[(ct * 64 + lane) * 8];
    #pragma unroll
    for (int kh = 0; kh < 2; ++kh)
        #pragma unroll
        for (int ct = 0; ct < 4; ++ct)
            w2f[kh][ct] = *(const bf16x8*)&w2p[((kh * 4 + ct) * 64 + lane) * 8];

    float4 b1v[4], b2v[4];
    #pragma unroll
    for (int ft = 0; ft < 4; ++ft) {
        b1v[ft] = *(const float4*)&b1[ft * 16 + g * 4];
        b2v[ft] = *(const float4*)&b2[ft * 16 + g * 4];
    }

    // stage 1 (swapped): C1[ft][pt] = W1^T x f_ij^T
    bf16x8 fijf[4];
    #pragma unroll
    for (int pt = 0; pt < 4; ++pt) {
        int row = pbase + wbase + pt * 16 + m;
        if (row >= P) row = (P > 0 ? P - 1 : 0);
        const float* srcp = f_ij + (size_t)row * R_ + g * 8;
        float4 f0 = *(const float4*)srcp;
        float4 f1 = *(const float4*)(srcp + 4);
        uint4 pk;
        pk.x = pkbf(f0.x, f0.y);
        pk.y = pkbf(f0.z, f0.w);
        pk.z = pkbf(f1.x, f1.y);
        pk.w = pkbf(f1.z, f1.w);
        bf16x8 av; __builtin_memcpy(&av, &pk, 16);
        fijf[pt] = av;
    }
    f32x4 C1[4][4];
    #pragma unroll
    for (int ft = 0; ft < 4; ++ft)
        #pragma unroll
        for (int pt = 0; pt < 4; ++pt) {
            f32x4 z = {0.f, 0.f, 0.f, 0.f};
            C1[ft][pt] = __builtin_amdgcn_mfma_f32_16x16x32_bf16(w1f[ft], fijf[pt], z, 0, 0, 0);
        }

    // ssp + packed-bf16 -> swizzled T
    #pragma unroll
    for (int ft = 0; ft < 4; ++ft)
        #pragma unroll
        for (int pt = 0; pt < 4; ++pt) {
            int wp = pt * 16 + m;
            float v0 = sspf(C1[ft][pt][0] + b1v[ft].x);
            float v1 = sspf(C1[ft][pt][1] + b1v[ft].y);
            float v2 = sspf(C1[ft][pt][2] + b1v[ft].z);
            float v3 = sspf(C1[ft][pt][3] + b1v[ft].w);
            uint2 tw;
            tw.x = pkbf(v0, v1);
            tw.y = pkbf(v2, v3);
            int c = (ft * 4 + g) ^ ((wp & 7) << 1);
            *(uint2*)&T[(wbase + wp) * 64 + c * 4] = tw;
        }

    // ---- stage 2 + epilogue, per-pt pipeline with 2-deep rolling h prefetch ----
    ushort4 hcur[4], hnxt[4];
    {
        int j_ = jj[wbase + m];                       // pt = 0
        const unsigned short* hrow = h + (size_t)j_ * F_;
        #pragma unroll
        for (int ft = 0; ft < 4; ++ft)
            hcur[ft] = *(const ushort4*)&hrow[ft * 16 + g * 4];
    }
    #pragma unroll
    for (int pt = 0; pt < 4; ++pt) {
        if (pt < 3) {                                 // issue next gather early
            int j_ = jj[wbase + (pt + 1) * 16 + m];
            const unsigned short* hrow = h + (size_t)j_ * F_;
            #pragma unroll
            for (int ft = 0; ft < 4; ++ft)
                hnxt[ft] = *(const ushort4*)&hrow[ft * 16 + g * 4];
        }

        int wpr = pt * 16 + m;
        int s = wpr & 7;
        const unsigned short* Trow = &T[(wbase + wpr) * 64];
        bf16x8 t0 = *(const bf16x8*)&Trow[((0 + g) ^ s) * 8];
        bf16x8 t1 = *(const bf16x8*)&Trow[((4 + g) ^ s) * 8];
        f32x4 C2f[4];
        #pragma unroll
        for (int ft = 0; ft < 4; ++ft) {
            f32x4 c = {0.f, 0.f, 0.f, 0.f};
            c = __builtin_amdgcn_mfma_f32_16x16x32_bf16(w2f[0][ft], t0, c, 0, 0, 0);
            c = __builtin_amdgcn_mfma_f32_16x16x32_bf16(w2f[1][ft], t1, c, 0, 0, 0);
            C2f[ft] = c;
        }

        int pp = wbase + pt * 16 + m;
        float rc = rr[pp];
        if (!ATOMIC) {
            unsigned short* xrow = xs + (size_t)ii[pp] * F_;   // CSR slot
            #pragma unroll
            for (int ft = 0; ft < 4; ++ft) {
                int f0 = ft * 16 + g * 4;
                ushort4 hv = hcur[ft];
                float x0 = (C2f[ft][0] + b2v[ft].x) * rc * bfbits2f(hv.x);
                float x1 = (C2f[ft][1] + b2v[ft].y) * rc * bfbits2f(hv.y);
                float x2 = (C2f[ft][2] + b2v[ft].z) * rc * bfbits2f(hv.z);
                float x3 = (C2f[ft][3] + b2v[ft].w) * rc * bfbits2f(hv.w);
                uint2 w;
                w.x = pkh(x0, x1);
                w.y = pkh(x2, x3);
                *(uint2*)&xrow[f0] = w;
            }
        } else {
            float* aggrow = agg_f32 + (size_t)ii[pp] * F_;
            #pragma unroll
            for (int ft = 0; ft < 4; ++ft) {
                int f0 = ft * 16 + g * 4;
                ushort4 hv = hcur[ft];
                atomicAdd(aggrow + f0 + 0, (C2f[ft][0] + b2v[ft].x) * rc * bfbits2f(hv.x));
                atomicAdd(aggrow + f0 + 1, (C2f[ft][1] + b2v[ft].y) * rc * bfbits2f(hv.y));
                atomicAdd(aggrow + f0 + 2, (C2f[ft][2] + b2v[ft].z) * rc * bfbits2f(hv.z));
                atomicAdd(aggrow + f0 + 3, (C2f[ft][3] + b2v[ft].w) * rc * bfbits2f(hv.w));
            }
        }
        #pragma unroll
        for (int ft = 0; ft < 4; ++ft) hcur[ft] = hnxt[ft];
    }
}

// ---- segment-sum: wave per atom, lane = feature, contiguous CSR; bf16 out ----
__global__ __launch_bounds__(256) void reduce_kernel(
    const unsigned short* __restrict__ xs, const int* __restrict__ off,
    unsigned short* __restrict__ aggb, int NA)
{
    int a = blockIdx.x * 4 + (threadIdx.x >> 6);
    int lane = threadIdx.x & 63;
    if (a >= NA) return;
    int s = off[a], e = off[a + 1];
    float a0 = 0.f, a1 = 0.f, a2 = 0.f, a3 = 0.f;
    int k = s;
    for (; k + 4 <= e; k += 4) {
        a0 += h16f(xs[(size_t)(k + 0) * F_ + lane]);
        a1 += h16f(xs[(size_t)(k + 1) * F_ + lane]);
        a2 += h16f(xs[(size_t)(k + 2) * F_ + lane]);
        a3 += h16f(xs[(size_t)(k + 3) * F_ + lane]);
    }
    for (; k < e; ++k) a0 += h16f(xs[(size_t)k * F_ + lane]);
    aggb[(size_t)a * F_ + lane] = (unsigned short)f2bf((a0 + a1) + (a2 + a3));
}

// ---- fused output head: out = ssp(agg@w_o1+b_o1)@w_o2+b_o2; u stays in LDS ----
template <bool AGGB>
__global__ __launch_bounds__(256) void out12_kernel(
    const void* __restrict__ agg_p,
    const unsigned short* __restrict__ wo1p, const float* __restrict__ b_o1,
    const unsigned short* __restrict__ wo2p, const float* __restrict__ b_o2,
    float* __restrict__ out, int NA)
{
    __shared__ __align__(16) unsigned short U[4][64][136];   // pad 136: 2-way banks

    const int tid  = threadIdx.x;
    const int lane = tid & 63;
    const int wv   = tid >> 6;
    const int g    = lane >> 4;
    const int m    = lane & 15;
    const int rbase = blockIdx.x * 256 + wv * 64;

    // step 1 (swapped MFMA): u[feat][row] tiles; lane holds 4 consecutive feats
    {
        bf16x8 wf[2][2][4];  // [ch][kh][ct]
        #pragma unroll
        for (int ch = 0; ch < 2; ++ch)
            #pragma unroll
            for (int kh = 0; kh < 2; ++kh)
                #pragma unroll
                for (int ct = 0; ct < 4; ++ct)
                    wf[ch][kh][ct] = *(const bf16x8*)&wo1p[(((ch * 2 + kh) * 4 + ct) * 64 + lane) * 8];
        float4 bo1[2][4];
        #pragma unroll
        for (int ch = 0; ch < 2; ++ch)
            #pragma unroll
            for (int ct = 0; ct < 4; ++ct)
                bo1[ch][ct] = *(const float4*)&b_o1[ch * 64 + ct * 16 + g * 4];

        #pragma unroll
        for (int rt = 0; rt < 4; ++rt) {
            int row = rbase + rt * 16 + m;
            if (row >= NA) row = NA - 1;
            bf16x8 af[2];
            #pragma unroll
            for (int kh = 0; kh < 2; ++kh) {
                if (AGGB) {
                    af[kh] = *(const bf16x8*)((const unsigned short*)agg_p + (size_t)row * F_ + kh * 32 + g * 8);
                } else {
                    const float* ar = (const float*)agg_p + (size_t)row * F_ + kh * 32 + g * 8;
                    float4 v0 = *(const float4*)ar;
                    float4 v1 = *(const float4*)(ar + 4);
                    uint4 pk;
                    pk.x = pkbf(v0.x, v0.y); pk.y = pkbf(v0.z, v0.w);
                    pk.z = pkbf(v1.x, v1.y); pk.w = pkbf(v1.z, v1.w);
                    bf16x8 av; __builtin_memcpy(&av, &pk, 16);
                    af[kh] = av;
                }
            }
            #pragma unroll
            for (int ch = 0; ch < 2; ++ch)
                #pragma unroll
                for (int ct = 0; ct < 4; ++ct) {
                    f32x4 c = {0.f, 0.f, 0.f, 0.f};
                    c = __builtin_amdgcn_mfma_f32_16x16x32_bf16(wf[ch][0][ct], af[0], c, 0, 0, 0);
                    c = __builtin_amdgcn_mfma_f32_16x16x32_bf16(wf[ch][1][ct], af[1], c, 0, 0, 0);
                    float u0 = sspf(c[0] + bo1[ch][ct].x);
                    float u1 = sspf(c[1] + bo1[ch][ct].y);
                    float u2 = sspf(c[2] + bo1[ch][ct].z);
                    float u3 = sspf(c[3] + bo1[ch][ct].w);
                    uint2 uw;
                    uw.x = pkbf(u0, u1);
                    uw.y = pkbf(u2, u3);
                    *(uint2*)&U[wv][rt * 16 + m][ch * 64 + ct * 16 + g * 4] = uw;
                }
        }
    }
    // same-wave LDS visibility (each wave touches only U[wv]) — no barrier needed

    // step 2: out rows = U @ w_o2 + b_o2
    #pragma unroll
    for (int ch = 0; ch < 2; ++ch) {
        bf16x8 wf2[4][4];
        #pragma unroll
        for (int kh = 0; kh < 4; ++kh)
            #pragma unroll
            for (int ct = 0; ct < 4; ++ct)
                wf2[kh][ct] = *(const bf16x8*)&wo2p[(((ch * 4 + kh) * 4 + ct) * 64 + lane) * 8];
        float bo2[4];
        #pragma unroll
        for (int ct = 0; ct < 4; ++ct) bo2[ct] = b_o2[ch * 64 + ct * 16 + m];

        #pragma unroll
        for (int rt = 0; rt < 4; ++rt) {
            bf16x8 af[4];
            #pragma unroll
            for (int kh = 0; kh < 4; ++kh)
                af[kh] = *(const bf16x8*)&U[wv][rt * 16 + m][kh * 32 + g * 8];
            #pragma unroll
            for (int ct = 0; ct < 4; ++ct) {
                f32x4 c = {0.f, 0.f, 0.f, 0.f};
                #pragma unroll
                for (int kh = 0; kh < 4; ++kh)
                    c = __builtin_amdgcn_mfma_f32_16x16x32_bf16(af[kh], wf2[kh][ct], c, 0, 0, 0);
                #pragma unroll
                for (int r = 0; r < 4; ++r) {
                    int ro = rbase + rt * 16 + g * 4 + r;
                    if (ro < NA)
                        out[(size_t)ro * B_ + ch * 64 + ct * 16 + m] = c[r] + bo2[ct];
                }
            }
        }
    }
}

extern "C" void kernel_launch(void* const* d_in, const int* in_sizes, int n_in,
                              void* d_out, int out_size, void* d_ws, size_t ws_size,
                              hipStream_t stream) {
    const float* x    = (const float*)d_in[0];
    const float* f_ij = (const float*)d_in[1];
    const float* rcut = (const float*)d_in[2];
    const void*  pl   = d_in[3];
    const float* w_in = (const float*)d_in[4];
    const float* b_in = (const float*)d_in[5];
    const float* w_f1 = (const float*)d_in[6];
    const float* b_f1 = (const float*)d_in[7];
    const float* w_f2 = (const float*)d_in[8];
    const float* b_f2 = (const float*)d_in[9];
    const float* w_o1 = (const float*)d_in[10];
    const float* b_o1 = (const float*)d_in[11];
    const float* w_o2 = (const float*)d_in[12];
    const float* b_o2 = (const float*)d_in[13];
    float* out = (float*)d_out;

    int NA = in_sizes[0] / B_;
    int P  = in_sizes[2];
    int nb = (NA + 2047) / 2048;
    int hgrid = (NA + 255) / 256;
    int pgrid = (P + 255) / 256;

    size_t hB    = (size_t)NA * F_ * 2;
    size_t xsB   = (size_t)(P + 256) * F_ * 2;
    size_t agB   = (size_t)NA * F_ * 2;
    size_t histB = (size_t)NA * 4;
    size_t offB  = (size_t)(NA + 1) * 4;
    size_t rkB   = (size_t)(P + 256) * 4;
    size_t wAll  = (2048 + 4096 + 8192 + 16384) * 2;
    size_t mainNeed = hB + xsB + agB + histB + offB + rkB + 1024 + wAll + 8192;

    bool CSR = (ws_size >= mainNeed) && (nb <= 256);

    char* ws = (char*)d_ws;
    size_t off_ = 0;
    auto alloc = [&](size_t bytes) { size_t o = off_; off_ = (off_ + bytes + 255) & ~(size_t)255; return o; };

    unsigned short* h_buf = (unsigned short*)(ws + alloc(hB));
    unsigned short* w1p   = (unsigned short*)(ws + alloc(2048 * 2));
    unsigned short* w2p   = (unsigned short*)(ws + alloc(4096 * 2));
    unsigned short* wo1p  = (unsigned short*)(ws + alloc(8192 * 2));
    unsigned short* wo2p  = (unsigned short*)(ws + alloc(16384 * 2));
    int* flag             = (int*)(ws + alloc(256));

    if (CSR) {
        unsigned short* xs   = (unsigned short*)(ws + alloc(xsB));
        unsigned short* aggb = (unsigned short*)(ws + alloc(agB));
        int* hist            = (int*)(ws + alloc(histB));
        int* off             = (int*)(ws + alloc(offB));
        int* rank            = (int*)(ws + alloc(rkB));
        int* bsum            = (int*)(ws + alloc(1024));

        (void)hipMemsetAsync(hist, 0, histB, stream);
        front_kernel<<<16 + hgrid + pgrid, 256, 0, stream>>>(
            w_f1, w_f2, w_o1, w_o2, w1p, w2p, wo1p, wo2p,
            pl, flag, P, x, w_in, b_in, h_buf, NA, hist, rank, hgrid);
        scan1_kernel<<<nb, 256, 0, stream>>>(hist, off, bsum, NA);
        scan2_kernel<<<1, 256, 0, stream>>>(bsum, nb);
        scan3_kernel<<<(NA + 1 + 255) / 256, 256, 0, stream>>>(off, bsum, NA, P);
        pair_kernel<false><<<pgrid, 256, 0, stream>>>(
            f_ij, rcut, pl, flag, w1p, b_f1, w2p, b_f2, h_buf, xs, rank, off, nullptr, P);
        reduce_kernel<<<(NA + 3) / 4, 256, 0, stream>>>(xs, off, aggb, NA);
        out12_kernel<true><<<hgrid, 256, 0, stream>>>(aggb, wo1p, b_o1, wo2p, b_o2, out, NA);
    } else {
        float* agg = (float*)(ws + alloc((size_t)NA * F_ * 4));
        (void)hipMemsetAsync(agg, 0, (size_t)NA * F_ * 4, stream);
        front_kernel<<<16 + hgrid, 256, 0, stream>>>(
            w_f1, w_f2, w_o1, w_o2, w1p, w2p, wo1p, wo2p,
            pl, flag, P, x, w_in, b_in, h_buf, NA, nullptr, nullptr, hgrid);
        pair_kernel<true><<<pgrid, 256, 0, stream>>>(
            f_ij, rcut, pl, flag, w1p, b_f1, w2p, b_f2, h_buf, nullptr, nullptr, nullptr, agg, P);
        out12_kernel<false><<<hgrid, 256, 0, stream>>>(agg, wo1p, b_o1, wo2p, b_o2, out, NA);
    }
}

// Round 20
// 332.099 us; speedup vs baseline: 1.4543x; 1.0917x over previous
//
#include <hip/hip_runtime.h>
#include <hip/hip_bf16.h>
#include <hip/hip_fp16.h>

#define B_ 128
#define F_ 64
#define R_ 32

typedef __attribute__((ext_vector_type(8))) __bf16 bf16x8;
typedef __attribute__((ext_vector_type(4))) float f32x4;

#define LN2F 0.6931471805599453f
#define L2EF 1.4426950408889634f

// ssp(x) = max(x,0) + ln2*log2(1+2^(-log2e*|x|)) - ln2   (overflow-safe all x)
__device__ __forceinline__ float sspf(float x) {
    float t = fabsf(x) * (-L2EF);
    float e; asm("v_exp_f32 %0, %1" : "=v"(e) : "v"(t));
    float l; asm("v_log_f32 %0, %1" : "=v"(l) : "v"(1.0f + e));
    return fmaxf(x, 0.0f) + fmaf(LN2F, l, -LN2F);
}
__device__ __forceinline__ float bfbits2f(unsigned int us) { return __uint_as_float(us << 16); }
__device__ __forceinline__ unsigned int f2bf(float f) {
    unsigned int u = __float_as_uint(f);
    return (u + 0x7fffu + ((u >> 16) & 1u)) >> 16;   // RNE
}
__device__ __forceinline__ float h16f(unsigned short s) { return __half2float(__ushort_as_half(s)); }
// packed HW conversions (v_cvt_pk_*): bit-pattern via memcpy (free)
__device__ __forceinline__ unsigned int pkbf(float a, float b) {
    __hip_bfloat162 h = __float22bfloat162_rn(make_float2(a, b));
    unsigned int r; __builtin_memcpy(&r, &h, 4); return r;
}
__device__ __forceinline__ unsigned int pkh(float a, float b) {
    __half2 h = __float22half2_rn(make_float2(a, b));
    unsigned int r; __builtin_memcpy(&r, &h, 4); return r;
}

// ---- front: prepack (0-14) + detect (15) + h via MFMA (hgrid) + hist+rank ----
__global__ __launch_bounds__(256) void front_kernel(
    const float* __restrict__ w1, const float* __restrict__ w2,
    const float* __restrict__ wo1, const float* __restrict__ wo2,
    unsigned short* __restrict__ w1p, unsigned short* __restrict__ w2p,
    unsigned short* __restrict__ wo1p, unsigned short* __restrict__ wo2p,
    const void* __restrict__ pl, int* __restrict__ flag, int P,
    const float* __restrict__ x, const float* __restrict__ w_in,
    const float* __restrict__ b_in, unsigned short* __restrict__ h, int NA,
    int* __restrict__ hist, int* __restrict__ rank, int hgrid)
{
    int b = blockIdx.x;
    if (b < 15) {
        int t = b * 256 + threadIdx.x;
        if (t < 256) {
            int ct = t >> 6, l = t & 63, g = l >> 4, m = l & 15;
            #pragma unroll
            for (int i = 0; i < 8; ++i)
                w1p[t * 8 + i] = (unsigned short)f2bf(w1[(g * 8 + i) * F_ + ct * 16 + m]);
        } else if (t < 768) {
            int q = t - 256;
            int kh = q >> 8, ct = (q >> 6) & 3, l = q & 63, g = l >> 4, m = l & 15;
            #pragma unroll
            for (int i = 0; i < 8; ++i)
                w2p[q * 8 + i] = (unsigned short)f2bf(w2[(kh * 32 + g * 8 + i) * F_ + ct * 16 + m]);
        } else if (t < 2816) {
            int q = t - 768;
            int l = q & 63, ct = (q >> 6) & 3, kh = (q >> 8) & 3, ch = q >> 10;
            int g = l >> 4, m = l & 15;
            #pragma unroll
            for (int i = 0; i < 8; ++i)
                wo2p[q * 8 + i] = (unsigned short)f2bf(wo2[(kh * 32 + g * 8 + i) * B_ + ch * 64 + ct * 16 + m]);
        } else if (t < 3840) {
            int q = t - 2816;
            int l = q & 63, ct = (q >> 6) & 3, kh = (q >> 8) & 1, ch = q >> 9;
            int g = l >> 4, m = l & 15;
            #pragma unroll
            for (int i = 0; i < 8; ++i)
                wo1p[q * 8 + i] = (unsigned short)f2bf(wo1[(kh * 32 + g * 8 + i) * B_ + ch * 64 + ct * 16 + m]);
        }
        return;
    }
    if (b == 15) {
        if (threadIdx.x < 64) {
            int n = (P < 64) ? P : 64;
            const long long* p64 = (const long long*)pl;
            bool bad = false;
            if ((int)threadIdx.x < n) {
                long long v = p64[threadIdx.x];
                bad = (v < 0) || (v >= 100000000LL);
            }
            unsigned long long bl = __ballot(bad);
            if (threadIdx.x == 0) *flag = (bl == 0ULL) ? 1 : 0;
        }
        return;
    }
    if (b < 16 + hgrid) {
        // h = x @ w_in + b_in via swapped MFMA: C[feat][row], K=128 (4 chained)
        const int lane = threadIdx.x & 63;
        const int wv   = threadIdx.x >> 6;
        const int g    = lane >> 4;
        const int m    = lane & 15;
        const int rbase = (b - 16) * 256 + wv * 64;

        // W-fragments (A-operand): wf[kh][ct][i] = w_in[(kh*32+g*8+i)][ct*16+m]
        bf16x8 wf[4][4];
        #pragma unroll
        for (int kh = 0; kh < 4; ++kh)
            #pragma unroll
            for (int ct = 0; ct < 4; ++ct) {
                const float* wp_ = w_in + (size_t)(kh * 32 + g * 8) * F_ + ct * 16 + m;
                uint4 pk;
                pk.x = pkbf(wp_[0 * F_], wp_[1 * F_]);
                pk.y = pkbf(wp_[2 * F_], wp_[3 * F_]);
                pk.z = pkbf(wp_[4 * F_], wp_[5 * F_]);
                pk.w = pkbf(wp_[6 * F_], wp_[7 * F_]);
                bf16x8 av; __builtin_memcpy(&av, &pk, 16);
                wf[kh][ct] = av;
            }
        float4 bv[4];
        #pragma unroll
        for (int ct = 0; ct < 4; ++ct) bv[ct] = *(const float4*)&b_in[ct * 16 + g * 4];

        #pragma unroll
        for (int rt = 0; rt < 4; ++rt) {
            int row = rbase + rt * 16 + m;
            int rowc = (row < NA) ? row : (NA - 1);
            const float* xr = x + (size_t)rowc * B_;
            bf16x8 xf[4];
            #pragma unroll
            for (int kh = 0; kh < 4; ++kh) {
                float4 f0 = *(const float4*)(xr + kh * 32 + g * 8);
                float4 f1 = *(const float4*)(xr + kh * 32 + g * 8 + 4);
                uint4 pk;
                pk.x = pkbf(f0.x, f0.y);
                pk.y = pkbf(f0.z, f0.w);
                pk.z = pkbf(f1.x, f1.y);
                pk.w = pkbf(f1.z, f1.w);
                bf16x8 av; __builtin_memcpy(&av, &pk, 16);
                xf[kh] = av;
            }
            #pragma unroll
            for (int ct = 0; ct < 4; ++ct) {
                f32x4 c = {0.f, 0.f, 0.f, 0.f};
                #pragma unroll
                for (int kh = 0; kh < 4; ++kh)
                    c = __builtin_amdgcn_mfma_f32_16x16x32_bf16(wf[kh][ct], xf[kh], c, 0, 0, 0);
                // C[feat = ct*16+g*4+r][row = rt*16+m]
                if (row < NA) {
                    uint2 hw;
                    hw.x = pkbf(c[0] + bv[ct].x, c[1] + bv[ct].y);
                    hw.y = pkbf(c[2] + bv[ct].z, c[3] + bv[ct].w);
                    *(uint2*)&h[(size_t)row * F_ + ct * 16 + g * 4] = hw;
                }
            }
        }
        return;
    }
    // hist blocks: block-local dtype detect; rank[p] = per-atom arrival order
    __shared__ int sflag;
    if (threadIdx.x < 64) {
        int n = (P < 64) ? P : 64;
        const long long* p64 = (const long long*)pl;
        bool bad = false;
        if ((int)threadIdx.x < n) {
            long long v = p64[threadIdx.x];
            bad = (v < 0) || (v >= 100000000LL);
        }
        unsigned long long bl = __ballot(bad);
        if (threadIdx.x == 0) sflag = (bl == 0ULL) ? 1 : 0;
    }
    __syncthreads();
    int p = (b - 16 - hgrid) * 256 + threadIdx.x;
    if (p >= P) return;
    int i = sflag ? (int)((const long long*)pl)[p] : ((const int*)pl)[p];
    rank[p] = atomicAdd(&hist[i], 1);
}

// ---- hierarchical scan, level 1 ----
__global__ __launch_bounds__(256) void scan1_kernel(
    const int* __restrict__ hist, int* __restrict__ off,
    int* __restrict__ bsum, int NA)
{
    __shared__ int s[256];
    int t = threadIdx.x;
    int idx = blockIdx.x * 2048 + t * 8;
    int v[8];
    int run = 0;
    #pragma unroll
    for (int k = 0; k < 8; ++k) {
        int i = idx + k;
        int c = (i < NA) ? hist[i] : 0;
        v[k] = run; run += c;
    }
    s[t] = run;
    __syncthreads();
    for (int o = 1; o < 256; o <<= 1) {
        int x = (t >= o) ? s[t - o] : 0;
        __syncthreads();
        s[t] += x;
        __syncthreads();
    }
    int base = (t == 0) ? 0 : s[t - 1];
    #pragma unroll
    for (int k = 0; k < 8; ++k) {
        int i = idx + k;
        if (i < NA) off[i] = v[k] + base;
    }
    if (t == 255) bsum[blockIdx.x] = s[255];
}

__global__ __launch_bounds__(256) void scan2_kernel(int* __restrict__ bsum, int nb) {
    __shared__ int s[256];
    int t = threadIdx.x;
    int v = (t < nb) ? bsum[t] : 0;
    s[t] = v;
    __syncthreads();
    for (int o = 1; o < 256; o <<= 1) {
        int x = (t >= o) ? s[t - o] : 0;
        __syncthreads();
        s[t] += x;
        __syncthreads();
    }
    if (t < nb) bsum[t] = s[t] - v;
}

__global__ __launch_bounds__(256) void scan3_kernel(
    int* __restrict__ off, const int* __restrict__ bsum, int NA, int P)
{
    int i = blockIdx.x * 256 + threadIdx.x;
    if (i > NA) return;
    if (i == NA) { off[NA] = P; return; }
    off[i] += bsum[i >> 11];
}

// ---- MFMA fused pair pipeline (v16): deterministic CSR slot (off+rank), ----
// rolling h-prefetch, modulated scattered xs[pos] store. NO contended atomics.
template <bool ATOMIC>
__global__ __launch_bounds__(256, 4) void pair_kernel(
    const float* __restrict__ f_ij, const float* __restrict__ rcut,
    const void* __restrict__ pl, const int* __restrict__ flag,
    const unsigned short* __restrict__ w1p, const float* __restrict__ b1,
    const unsigned short* __restrict__ w2p, const float* __restrict__ b2,
    const unsigned short* __restrict__ h, unsigned short* __restrict__ xs,
    const int* __restrict__ rank, const int* __restrict__ off,
    float* __restrict__ agg_f32, int P)
{
    __shared__ __align__(16) unsigned short T[256 * 64];
    __shared__ __align__(16) int   ii[256];   // ATOMIC: atom idx; CSR: slot pos
    __shared__ __align__(16) int   jj[256];
    __shared__ __align__(16) float rr[256];

    const int tid   = threadIdx.x;
    const int lane  = tid & 63;
    const int wv    = tid >> 6;
    const int g     = lane >> 4;
    const int m     = lane & 15;
    const int pbase = blockIdx.x * 256;
    const int wbase = wv * 64;

    {
        int p = pbase + tid;
        bool valid = (p < P);
        int pc = valid ? p : (P > 0 ? P - 1 : 0);
        long long i_, j_;
        if (*flag) {
            const long long* p64 = (const long long*)pl;
            i_ = p64[pc]; j_ = p64[(size_t)P + pc];
        } else {
            const int* p32 = (const int*)pl;
            i_ = p32[pc]; j_ = p32[(size_t)P + pc];
        }
        jj[tid] = valid ? (int)j_ : 0;
        rr[tid] = valid ? rcut[pc] : 0.0f;
        if (ATOMIC) {
            ii[tid] = valid ? (int)i_ : 0;
        } else {
            ii[tid] = valid ? (off[(int)i_] + rank[pc]) : (P + tid);
        }
    }

    bf16x8 w1f[4], w2f[2][4];
    #pragma unroll
    for (int ct = 0; ct < 4; ++ct)
        w1f[ct] = *(const bf16x8*)&w1p[(ct * 64 + lane) * 8];
    #pragma unroll
    for (int kh = 0; kh < 2; ++kh)
        #pragma unroll
        for (int ct = 0; ct < 4; ++ct)
            w2f[kh][ct] = *(const bf16x8*)&w2p[((kh * 4 + ct) * 64 + lane) * 8];

    float4 b1v[4], b2v[4];
    #pragma unroll
    for (int ft = 0; ft < 4; ++ft) {
        b1v[ft] = *(const float4*)&b1[ft * 16 + g * 4];
        b2v[ft] = *(const float4*)&b2[ft * 16 + g * 4];
    }

    // stage 1 (swapped): C1[ft][pt] = W1^T x f_ij^T
    bf16x8 fijf[4];
    #pragma unroll
    for (int pt = 0; pt < 4; ++pt) {
        int row = pbase + wbase + pt * 16 + m;
        if (row >= P) row = (P > 0 ? P - 1 : 0);
        const float* srcp = f_ij + (size_t)row * R_ + g * 8;
        float4 f0 = *(const float4*)srcp;
        float4 f1 = *(const float4*)(srcp + 4);
        uint4 pk;
        pk.x = pkbf(f0.x, f0.y);
        pk.y = pkbf(f0.z, f0.w);
        pk.z = pkbf(f1.x, f1.y);
        pk.w = pkbf(f1.z, f1.w);
        bf16x8 av; __builtin_memcpy(&av, &pk, 16);
        fijf[pt] = av;
    }
    f32x4 C1[4][4];
    #pragma unroll
    for (int ft = 0; ft < 4; ++ft)
        #pragma unroll
        for (int pt = 0; pt < 4; ++pt) {
            f32x4 z = {0.f, 0.f, 0.f, 0.f};
            C1[ft][pt] = __builtin_amdgcn_mfma_f32_16x16x32_bf16(w1f[ft], fijf[pt], z, 0, 0, 0);
        }

    // ssp + packed-bf16 -> swizzled T
    #pragma unroll
    for (int ft = 0; ft < 4; ++ft)
        #pragma unroll
        for (int pt = 0; pt < 4; ++pt) {
            int wp = pt * 16 + m;
            float v0 = sspf(C1[ft][pt][0] + b1v[ft].x);
            float v1 = sspf(C1[ft][pt][1] + b1v[ft].y);
            float v2 = sspf(C1[ft][pt][2] + b1v[ft].z);
            float v3 = sspf(C1[ft][pt][3] + b1v[ft].w);
            uint2 tw;
            tw.x = pkbf(v0, v1);
            tw.y = pkbf(v2, v3);
            int c = (ft * 4 + g) ^ ((wp & 7) << 1);
            *(uint2*)&T[(wbase + wp) * 64 + c * 4] = tw;
        }

    // ---- stage 2 + epilogue, per-pt pipeline with 2-deep rolling h prefetch ----
    ushort4 hcur[4], hnxt[4];
    {
        int j_ = jj[wbase + m];                       // pt = 0
        const unsigned short* hrow = h + (size_t)j_ * F_;
        #pragma unroll
        for (int ft = 0; ft < 4; ++ft)
            hcur[ft] = *(const ushort4*)&hrow[ft * 16 + g * 4];
    }
    #pragma unroll
    for (int pt = 0; pt < 4; ++pt) {
        if (pt < 3) {                                 // issue next gather early
            int j_ = jj[wbase + (pt + 1) * 16 + m];
            const unsigned short* hrow = h + (size_t)j_ * F_;
            #pragma unroll
            for (int ft = 0; ft < 4; ++ft)
                hnxt[ft] = *(const ushort4*)&hrow[ft * 16 + g * 4];
        }

        int wpr = pt * 16 + m;
        int s = wpr & 7;
        const unsigned short* Trow = &T[(wbase + wpr) * 64];
        bf16x8 t0 = *(const bf16x8*)&Trow[((0 + g) ^ s) * 8];
        bf16x8 t1 = *(const bf16x8*)&Trow[((4 + g) ^ s) * 8];
        f32x4 C2f[4];
        #pragma unroll
        for (int ft = 0; ft < 4; ++ft) {
            f32x4 c = {0.f, 0.f, 0.f, 0.f};
            c = __builtin_amdgcn_mfma_f32_16x16x32_bf16(w2f[0][ft], t0, c, 0, 0, 0);
            c = __builtin_amdgcn_mfma_f32_16x16x32_bf16(w2f[1][ft], t1, c, 0, 0, 0);
            C2f[ft] = c;
        }

        int pp = wbase + pt * 16 + m;
        float rc = rr[pp];
        if (!ATOMIC) {
            unsigned short* xrow = xs + (size_t)ii[pp] * F_;   // CSR slot
            #pragma unroll
            for (int ft = 0; ft < 4; ++ft) {
                int f0 = ft * 16 + g * 4;
                ushort4 hv = hcur[ft];
                float x0 = (C2f[ft][0] + b2v[ft].x) * rc * bfbits2f(hv.x);
                float x1 = (C2f[ft][1] + b2v[ft].y) * rc * bfbits2f(hv.y);
                float x2 = (C2f[ft][2] + b2v[ft].z) * rc * bfbits2f(hv.z);
                float x3 = (C2f[ft][3] + b2v[ft].w) * rc * bfbits2f(hv.w);
                uint2 w;
                w.x = pkh(x0, x1);
                w.y = pkh(x2, x3);
                *(uint2*)&xrow[f0] = w;
            }
        } else {
            float* aggrow = agg_f32 + (size_t)ii[pp] * F_;
            #pragma unroll
            for (int ft = 0; ft < 4; ++ft) {
                int f0 = ft * 16 + g * 4;
                ushort4 hv = hcur[ft];
                atomicAdd(aggrow + f0 + 0, (C2f[ft][0] + b2v[ft].x) * rc * bfbits2f(hv.x));
                atomicAdd(aggrow + f0 + 1, (C2f[ft][1] + b2v[ft].y) * rc * bfbits2f(hv.y));
                atomicAdd(aggrow + f0 + 2, (C2f[ft][2] + b2v[ft].z) * rc * bfbits2f(hv.z));
                atomicAdd(aggrow + f0 + 3, (C2f[ft][3] + b2v[ft].w) * rc * bfbits2f(hv.w));
            }
        }
        #pragma unroll
        for (int ft = 0; ft < 4; ++ft) hcur[ft] = hnxt[ft];
    }
}

// ---- segment-sum: wave per atom, lane = feature, contiguous CSR; bf16 out ----
__global__ __launch_bounds__(256) void reduce_kernel(
    const unsigned short* __restrict__ xs, const int* __restrict__ off,
    unsigned short* __restrict__ aggb, int NA)
{
    int a = blockIdx.x * 4 + (threadIdx.x >> 6);
    int lane = threadIdx.x & 63;
    if (a >= NA) return;
    int s = off[a], e = off[a + 1];
    float a0 = 0.f, a1 = 0.f, a2 = 0.f, a3 = 0.f;
    int k = s;
    for (; k + 4 <= e; k += 4) {
        a0 += h16f(xs[(size_t)(k + 0) * F_ + lane]);
        a1 += h16f(xs[(size_t)(k + 1) * F_ + lane]);
        a2 += h16f(xs[(size_t)(k + 2) * F_ + lane]);
        a3 += h16f(xs[(size_t)(k + 3) * F_ + lane]);
    }
    for (; k < e; ++k) a0 += h16f(xs[(size_t)k * F_ + lane]);
    aggb[(size_t)a * F_ + lane] = (unsigned short)f2bf((a0 + a1) + (a2 + a3));
}

// ---- fused output head: out = ssp(agg@w_o1+b_o1)@w_o2+b_o2; u stays in LDS ----
template <bool AGGB>
__global__ __launch_bounds__(256) void out12_kernel(
    const void* __restrict__ agg_p,
    const unsigned short* __restrict__ wo1p, const float* __restrict__ b_o1,
    const unsigned short* __restrict__ wo2p, const float* __restrict__ b_o2,
    float* __restrict__ out, int NA)
{
    __shared__ __align__(16) unsigned short U[4][64][136];   // pad 136: 2-way banks

    const int tid  = threadIdx.x;
    const int lane = tid & 63;
    const int wv   = tid >> 6;
    const int g    = lane >> 4;
    const int m    = lane & 15;
    const int rbase = blockIdx.x * 256 + wv * 64;

    // step 1 (swapped MFMA): u[feat][row] tiles; lane holds 4 consecutive feats
    {
        bf16x8 wf[2][2][4];  // [ch][kh][ct]
        #pragma unroll
        for (int ch = 0; ch < 2; ++ch)
            #pragma unroll
            for (int kh = 0; kh < 2; ++kh)
                #pragma unroll
                for (int ct = 0; ct < 4; ++ct)
                    wf[ch][kh][ct] = *(const bf16x8*)&wo1p[(((ch * 2 + kh) * 4 + ct) * 64 + lane) * 8];
        float4 bo1[2][4];
        #pragma unroll
        for (int ch = 0; ch < 2; ++ch)
            #pragma unroll
            for (int ct = 0; ct < 4; ++ct)
                bo1[ch][ct] = *(const float4*)&b_o1[ch * 64 + ct * 16 + g * 4];

        #pragma unroll
        for (int rt = 0; rt < 4; ++rt) {
            int row = rbase + rt * 16 + m;
            if (row >= NA) row = NA - 1;
            bf16x8 af[2];
            #pragma unroll
            for (int kh = 0; kh < 2; ++kh) {
                if (AGGB) {
                    af[kh] = *(const bf16x8*)((const unsigned short*)agg_p + (size_t)row * F_ + kh * 32 + g * 8);
                } else {
                    const float* ar = (const float*)agg_p + (size_t)row * F_ + kh * 32 + g * 8;
                    float4 v0 = *(const float4*)ar;
                    float4 v1 = *(const float4*)(ar + 4);
                    uint4 pk;
                    pk.x = pkbf(v0.x, v0.y); pk.y = pkbf(v0.z, v0.w);
                    pk.z = pkbf(v1.x, v1.y); pk.w = pkbf(v1.z, v1.w);
                    bf16x8 av; __builtin_memcpy(&av, &pk, 16);
                    af[kh] = av;
                }
            }
            #pragma unroll
            for (int ch = 0; ch < 2; ++ch)
                #pragma unroll
                for (int ct = 0; ct < 4; ++ct) {
                    f32x4 c = {0.f, 0.f, 0.f, 0.f};
                    c = __builtin_amdgcn_mfma_f32_16x16x32_bf16(wf[ch][0][ct], af[0], c, 0, 0, 0);
                    c = __builtin_amdgcn_mfma_f32_16x16x32_bf16(wf[ch][1][ct], af[1], c, 0, 0, 0);
                    float u0 = sspf(c[0] + bo1[ch][ct].x);
                    float u1 = sspf(c[1] + bo1[ch][ct].y);
                    float u2 = sspf(c[2] + bo1[ch][ct].z);
                    float u3 = sspf(c[3] + bo1[ch][ct].w);
                    uint2 uw;
                    uw.x = pkbf(u0, u1);
                    uw.y = pkbf(u2, u3);
                    *(uint2*)&U[wv][rt * 16 + m][ch * 64 + ct * 16 + g * 4] = uw;
                }
        }
    }
    // same-wave LDS visibility (each wave touches only U[wv]) — no barrier needed

    // step 2: out rows = U @ w_o2 + b_o2
    #pragma unroll
    for (int ch = 0; ch < 2; ++ch) {
        bf16x8 wf2[4][4];
        #pragma unroll
        for (int kh = 0; kh < 4; ++kh)
            #pragma unroll
            for (int ct = 0; ct < 4; ++ct)
                wf2[kh][ct] = *(const bf16x8*)&wo2p[(((ch * 4 + kh) * 4 + ct) * 64 + lane) * 8];
        float bo2[4];
        #pragma unroll
        for (int ct = 0; ct < 4; ++ct) bo2[ct] = b_o2[ch * 64 + ct * 16 + m];

        #pragma unroll
        for (int rt = 0; rt < 4; ++rt) {
            bf16x8 af[4];
            #pragma unroll
            for (int kh = 0; kh < 4; ++kh)
                af[kh] = *(const bf16x8*)&U[wv][rt * 16 + m][kh * 32 + g * 8];
            #pragma unroll
            for (int ct = 0; ct < 4; ++ct) {
                f32x4 c = {0.f, 0.f, 0.f, 0.f};
                #pragma unroll
                for (int kh = 0; kh < 4; ++kh)
                    c = __builtin_amdgcn_mfma_f32_16x16x32_bf16(af[kh], wf2[kh][ct], c, 0, 0, 0);
                #pragma unroll
                for (int r = 0; r < 4; ++r) {
                    int ro = rbase + rt * 16 + g * 4 + r;
                    if (ro < NA)
                        out[(size_t)ro * B_ + ch * 64 + ct * 16 + m] = c[r] + bo2[ct];
                }
            }
        }
    }
}

extern "C" void kernel_launch(void* const* d_in, const int* in_sizes, int n_in,
                              void* d_out, int out_size, void* d_ws, size_t ws_size,
                              hipStream_t stream) {
    const float* x    = (const float*)d_in[0];
    const float* f_ij = (const float*)d_in[1];
    const float* rcut = (const float*)d_in[2];
    const void*  pl   = d_in[3];
    const float* w_in = (const float*)d_in[4];
    const float* b_in = (const float*)d_in[5];
    const float* w_f1 = (const float*)d_in[6];
    const float* b_f1 = (const float*)d_in[7];
    const float* w_f2 = (const float*)d_in[8];
    const float* b_f2 = (const float*)d_in[9];
    const float* w_o1 = (const float*)d_in[10];
    const float* b_o1 = (const float*)d_in[11];
    const float* w_o2 = (const float*)d_in[12];
    const float* b_o2 = (const float*)d_in[13];
    float* out = (float*)d_out;

    int NA = in_sizes[0] / B_;
    int P  = in_sizes[2];
    int nb = (NA + 2047) / 2048;
    int hgrid = (NA + 255) / 256;
    int pgrid = (P + 255) / 256;

    size_t hB    = (size_t)NA * F_ * 2;
    size_t xsB   = (size_t)(P + 256) * F_ * 2;
    size_t agB   = (size_t)NA * F_ * 2;
    size_t histB = (size_t)NA * 4;
    size_t offB  = (size_t)(NA + 1) * 4;
    size_t rkB   = (size_t)(P + 256) * 4;
    size_t wAll  = (2048 + 4096 + 8192 + 16384) * 2;
    size_t mainNeed = hB + xsB + agB + histB + offB + rkB + 1024 + wAll + 8192;

    bool CSR = (ws_size >= mainNeed) && (nb <= 256);

    char* ws = (char*)d_ws;
    size_t off_ = 0;
    auto alloc = [&](size_t bytes) { size_t o = off_; off_ = (off_ + bytes + 255) & ~(size_t)255; return o; };

    unsigned short* h_buf = (unsigned short*)(ws + alloc(hB));
    unsigned short* w1p   = (unsigned short*)(ws + alloc(2048 * 2));
    unsigned short* w2p   = (unsigned short*)(ws + alloc(4096 * 2));
    unsigned short* wo1p  = (unsigned short*)(ws + alloc(8192 * 2));
    unsigned short* wo2p  = (unsigned short*)(ws + alloc(16384 * 2));
    int* flag             = (int*)(ws + alloc(256));

    if (CSR) {
        unsigned short* xs   = (unsigned short*)(ws + alloc(xsB));
        unsigned short* aggb = (unsigned short*)(ws + alloc(agB));
        int* hist            = (int*)(ws + alloc(histB));
        int* off             = (int*)(ws + alloc(offB));
        int* rank            = (int*)(ws + alloc(rkB));
        int* bsum            = (int*)(ws + alloc(1024));

        (void)hipMemsetAsync(hist, 0, histB, stream);
        front_kernel<<<16 + hgrid + pgrid, 256, 0, stream>>>(
            w_f1, w_f2, w_o1, w_o2, w1p, w2p, wo1p, wo2p,
            pl, flag, P, x, w_in, b_in, h_buf, NA, hist, rank, hgrid);
        scan1_kernel<<<nb, 256, 0, stream>>>(hist, off, bsum, NA);
        scan2_kernel<<<1, 256, 0, stream>>>(bsum, nb);
        scan3_kernel<<<(NA + 1 + 255) / 256, 256, 0, stream>>>(off, bsum, NA, P);
        pair_kernel<false><<<pgrid, 256, 0, stream>>>(
            f_ij, rcut, pl, flag, w1p, b_f1, w2p, b_f2, h_buf, xs, rank, off, nullptr, P);
        reduce_kernel<<<(NA + 3) / 4, 256, 0, stream>>>(xs, off, aggb, NA);
        out12_kernel<true><<<hgrid, 256, 0, stream>>>(aggb, wo1p, b_o1, wo2p, b_o2, out, NA);
    } else {
        float* agg = (float*)(ws + alloc((size_t)NA * F_ * 4));
        (void)hipMemsetAsync(agg, 0, (size_t)NA * F_ * 4, stream);
        front_kernel<<<16 + hgrid, 256, 0, stream>>>(
            w_f1, w_f2, w_o1, w_o2, w1p, w2p, wo1p, wo2p,
            pl, flag, P, x, w_in, b_in, h_buf, NA, nullptr, nullptr, hgrid);
        pair_kernel<true><<<pgrid, 256, 0, stream>>>(
            f_ij, rcut, pl, flag, w1p, b_f1, w2p, b_f2, h_buf, nullptr, nullptr, nullptr, agg, P);
        out12_kernel<false><<<hgrid, 256, 0, stream>>>(agg, wo1p, b_o1, wo2p, b_o2, out, NA);
    }
}